// Round 1
// baseline (2142.156 us; speedup 1.0000x reference)
//
#include <hip/hip_runtime.h>
#include <math.h>

#define L_SEQ 2048
#define DM 1024      // D_MODEL
#define DI 2048      // D_INNER
#define DS 16        // D_STATE
#define DR 64        // DT_RANK
#define XDN 96       // DT_RANK + 2*D_STATE

// ---------------- LayerNorm: one block per row ----------------
__global__ void ln_kernel(const float* __restrict__ x,
                          const float* __restrict__ gamma,
                          const float* __restrict__ beta,
                          float* __restrict__ xn) {
  int row = blockIdx.x;
  int t = threadIdx.x;
  const float4* xr = (const float4*)(x + (size_t)row * DM);
  float4 v = xr[t];
  float s = v.x + v.y + v.z + v.w;
  float s2 = v.x * v.x + v.y * v.y + v.z * v.z + v.w * v.w;
#pragma unroll
  for (int off = 32; off > 0; off >>= 1) {
    s += __shfl_down(s, off);
    s2 += __shfl_down(s2, off);
  }
  __shared__ float ls[4], ls2[4];
  if ((t & 63) == 0) { ls[t >> 6] = s; ls2[t >> 6] = s2; }
  __syncthreads();
  float tot = ls[0] + ls[1] + ls[2] + ls[3];
  float tot2 = ls2[0] + ls2[1] + ls2[2] + ls2[3];
  float mu = tot * (1.0f / DM);
  float var = tot2 * (1.0f / DM) - mu * mu;
  float r = rsqrtf(var + 1e-5f);
  float4 g = ((const float4*)gamma)[t];
  float4 b = ((const float4*)beta)[t];
  float4 o;
  o.x = (v.x - mu) * r * g.x + b.x;
  o.y = (v.y - mu) * r * g.y + b.y;
  o.z = (v.z - mu) * r * g.z + b.z;
  o.w = (v.w - mu) * r * g.w + b.w;
  ((float4*)(xn + (size_t)row * DM))[t] = o;
}

// ---------------- Generic fp32 GEMM: C[M,N] = A[M,K] * B[N,K]^T ----------------
// EPI 0: none; 1: softplus(v + extra[col]); 2: v + extra[row*lde + col]
// Requirements used here: M % 64 == 0, K % 16 == 0, A/B rows 16B-aligned.
template <int EPI>
__global__ void gemm_bt(const float* __restrict__ A, int lda,
                        const float* __restrict__ B, int ldb,
                        float* __restrict__ C, int ldc,
                        int M, int N, int K,
                        const float* __restrict__ extra, int lde) {
  __shared__ float As[16][68];  // [k][m], pad 68 to break conflicts
  __shared__ float Bs[16][68];  // [k][n]
  const int tid = threadIdx.x;
  const int tx = tid & 15;
  const int ty = tid >> 4;
  const int m0 = blockIdx.y * 64;
  const int n0 = blockIdx.x * 64;
  const int lm = tid >> 2;         // 0..63
  const int lk = (tid & 3) << 2;   // 0,4,8,12
  float acc[4][4] = {};
  for (int k0 = 0; k0 < K; k0 += 16) {
    float4 va = *(const float4*)(A + (size_t)(m0 + lm) * lda + k0 + lk);
    float4 vb = make_float4(0.f, 0.f, 0.f, 0.f);
    if (n0 + lm < N) vb = *(const float4*)(B + (size_t)(n0 + lm) * ldb + k0 + lk);
    __syncthreads();  // previous iteration's reads complete
    As[lk + 0][lm] = va.x; As[lk + 1][lm] = va.y;
    As[lk + 2][lm] = va.z; As[lk + 3][lm] = va.w;
    Bs[lk + 0][lm] = vb.x; Bs[lk + 1][lm] = vb.y;
    Bs[lk + 2][lm] = vb.z; Bs[lk + 3][lm] = vb.w;
    __syncthreads();
#pragma unroll
    for (int k = 0; k < 16; ++k) {
      float4 a = *(const float4*)&As[k][ty << 2];
      float4 b = *(const float4*)&Bs[k][tx << 2];
      float av[4] = {a.x, a.y, a.z, a.w};
      float bv[4] = {b.x, b.y, b.z, b.w};
#pragma unroll
      for (int i = 0; i < 4; ++i)
#pragma unroll
        for (int j = 0; j < 4; ++j)
          acc[i][j] += av[i] * bv[j];
    }
  }
#pragma unroll
  for (int i = 0; i < 4; ++i) {
    int row = m0 + (ty << 2) + i;
#pragma unroll
    for (int j = 0; j < 4; ++j) {
      int col = n0 + (tx << 2) + j;
      if (col < N) {
        float v = acc[i][j];
        if (EPI == 1) {
          v += extra[col];
          v = (v > 20.f) ? v : log1pf(expf(v));
        }
        if (EPI == 2) {
          v += extra[(size_t)row * lde + col];
        }
        C[(size_t)row * ldc + col] = v;
      }
    }
  }
}

// ---------------- causal depthwise conv (width 4) + bias + SiLU ----------------
// x_part = xz[:, 0:DI] (row stride 2*DI)
__global__ void conv_silu_kernel(const float* __restrict__ xz,
                                 const float* __restrict__ conv_w,
                                 const float* __restrict__ conv_b,
                                 float* __restrict__ xconv) {
  int idx = blockIdx.x * blockDim.x + threadIdx.x;
  if (idx >= L_SEQ * DI) return;
  int d = idx & (DI - 1);
  int t = idx >> 11;  // DI == 2^11
  float acc = conv_b[d];
  const float4 w = *(const float4*)(conv_w + (size_t)d * 4);
  float wv[4] = {w.x, w.y, w.z, w.w};
#pragma unroll
  for (int j = 0; j < 4; ++j) {
    int tt = t - 3 + j;
    if (tt >= 0) acc += xz[(size_t)tt * (2 * DI) + d] * wv[j];
  }
  xconv[idx] = acc / (1.f + expf(-acc));  // silu
}

// ---------------- selective scan, sequential over L ----------------
// 16 lanes per channel d; lane = state index n. h kept in a register.
// y[t,d] = sum_n(h*C) + u*Dp[d]; gated by silu(z).
__global__ void scan_kernel(const float* __restrict__ delta,
                            const float* __restrict__ u,
                            const float* __restrict__ xdbl,
                            const float* __restrict__ xz,
                            const float* __restrict__ A_log,
                            const float* __restrict__ Dp,
                            float* __restrict__ yg) {
  int lane = threadIdx.x & 15;
  int grp = threadIdx.x >> 4;  // 16 channels per block
  int d = blockIdx.x * 16 + grp;
  float Aval = -expf(A_log[(size_t)d * DS + lane]);
  float Dval = Dp[d];
  float h = 0.f;
  for (int t = 0; t < L_SEQ; ++t) {
    float dlt = delta[(size_t)t * DI + d];
    float uv = u[(size_t)t * DI + d];
    float Bv = xdbl[(size_t)t * XDN + DR + lane];
    float Cv = xdbl[(size_t)t * XDN + DR + DS + lane];
    float dA = expf(dlt * Aval);
    h = dA * h + dlt * Bv * uv;
    float c = h * Cv;
#pragma unroll
    for (int off = 1; off < 16; off <<= 1) c += __shfl_xor(c, off, 16);
    if (lane == 0) {
      float y = c + uv * Dval;
      float z = xz[(size_t)t * (2 * DI) + DI + d];
      float sz = z / (1.f + expf(-z));
      yg[(size_t)t * DI + d] = y * sz;
    }
  }
}

extern "C" void kernel_launch(void* const* d_in, const int* in_sizes, int n_in,
                              void* d_out, int out_size, void* d_ws, size_t ws_size,
                              hipStream_t stream) {
  const float* x = (const float*)d_in[0];
  const float* gamma = (const float*)d_in[1];
  const float* beta = (const float*)d_in[2];
  const float* w_in = (const float*)d_in[3];
  const float* conv_w = (const float*)d_in[4];
  const float* conv_b = (const float*)d_in[5];
  const float* w_x = (const float*)d_in[6];
  const float* w_dt = (const float*)d_in[7];
  const float* b_dt = (const float*)d_in[8];
  const float* A_log = (const float*)d_in[9];
  const float* Dp = (const float*)d_in[10];
  const float* w_out = (const float*)d_in[11];
  float* out = (float*)d_out;

  float* ws = (float*)d_ws;
  float* xn = ws;                       // 2048*1024
  float* xz = xn + L_SEQ * DM;          // 2048*4096
  float* xconv = xz + L_SEQ * 2 * DI;   // 2048*2048
  float* xdbl = xconv + L_SEQ * DI;     // 2048*96
  float* delta = xdbl + L_SEQ * XDN;    // 2048*2048
  float* yg = delta + L_SEQ * DI;       // 2048*2048

  // 1. LayerNorm
  ln_kernel<<<L_SEQ, 256, 0, stream>>>(x, gamma, beta, xn);
  // 2. xz = xn @ w_in^T   (2048 x 4096, K=1024)
  gemm_bt<0><<<dim3((2 * DI) / 64, L_SEQ / 64), 256, 0, stream>>>(
      xn, DM, w_in, DM, xz, 2 * DI, L_SEQ, 2 * DI, DM, nullptr, 0);
  // 3. conv + silu -> xconv (2048 x 2048)
  conv_silu_kernel<<<(L_SEQ * DI) / 256, 256, 0, stream>>>(xz, conv_w, conv_b, xconv);
  // 4. x_dbl = xconv @ w_x^T  (2048 x 96, K=2048)
  gemm_bt<0><<<dim3((XDN + 63) / 64, L_SEQ / 64), 256, 0, stream>>>(
      xconv, DI, w_x, DI, xdbl, XDN, L_SEQ, XDN, DI, nullptr, 0);
  // 5. delta = softplus(dt @ w_dt^T + b_dt)  (2048 x 2048, K=64)
  gemm_bt<1><<<dim3(DI / 64, L_SEQ / 64), 256, 0, stream>>>(
      xdbl, XDN, w_dt, DR, delta, DI, L_SEQ, DI, DR, b_dt, 0);
  // 6. selective scan + gate
  scan_kernel<<<DI / 16, 256, 0, stream>>>(delta, xconv, xdbl, xz, A_log, Dp, yg);
  // 7. out = yg @ w_out^T + residual  (2048 x 1024, K=2048)
  gemm_bt<2><<<dim3(DM / 64, L_SEQ / 64), 256, 0, stream>>>(
      yg, DI, w_out, DI, out, DM, L_SEQ, DM, DI, x, DM);
}

// Round 2
// 675.888 us; speedup vs baseline: 3.1694x; 3.1694x over previous
//
#include <hip/hip_runtime.h>
#include <math.h>

#define L_SEQ 2048
#define DM 1024      // D_MODEL
#define DI 2048      // D_INNER
#define DS 16        // D_STATE
#define DR 64        // DT_RANK
#define XDN 96       // DT_RANK + 2*D_STATE
#define NCHUNK 64
#define TCH 32       // L_SEQ / NCHUNK

// ---------------- LayerNorm: one block per row ----------------
__global__ void ln_kernel(const float* __restrict__ x,
                          const float* __restrict__ gamma,
                          const float* __restrict__ beta,
                          float* __restrict__ xn) {
  int row = blockIdx.x;
  int t = threadIdx.x;
  const float4* xr = (const float4*)(x + (size_t)row * DM);
  float4 v = xr[t];
  float s = v.x + v.y + v.z + v.w;
  float s2 = v.x * v.x + v.y * v.y + v.z * v.z + v.w * v.w;
#pragma unroll
  for (int off = 32; off > 0; off >>= 1) {
    s += __shfl_down(s, off);
    s2 += __shfl_down(s2, off);
  }
  __shared__ float ls[4], ls2[4];
  if ((t & 63) == 0) { ls[t >> 6] = s; ls2[t >> 6] = s2; }
  __syncthreads();
  float tot = ls[0] + ls[1] + ls[2] + ls[3];
  float tot2 = ls2[0] + ls2[1] + ls2[2] + ls2[3];
  float mu = tot * (1.0f / DM);
  float var = tot2 * (1.0f / DM) - mu * mu;
  float r = rsqrtf(var + 1e-5f);
  float4 g = ((const float4*)gamma)[t];
  float4 b = ((const float4*)beta)[t];
  float4 o;
  o.x = (v.x - mu) * r * g.x + b.x;
  o.y = (v.y - mu) * r * g.y + b.y;
  o.z = (v.z - mu) * r * g.z + b.z;
  o.w = (v.w - mu) * r * g.w + b.w;
  ((float4*)(xn + (size_t)row * DM))[t] = o;
}

// ---------------- Generic fp32 GEMM: C[M,N] = A[M,K] * B[N,K]^T ----------------
template <int EPI>
__global__ void gemm_bt(const float* __restrict__ A, int lda,
                        const float* __restrict__ B, int ldb,
                        float* __restrict__ C, int ldc,
                        int M, int N, int K,
                        const float* __restrict__ extra, int lde) {
  __shared__ float As[16][68];
  __shared__ float Bs[16][68];
  const int tid = threadIdx.x;
  const int tx = tid & 15;
  const int ty = tid >> 4;
  const int m0 = blockIdx.y * 64;
  const int n0 = blockIdx.x * 64;
  const int lm = tid >> 2;
  const int lk = (tid & 3) << 2;
  float acc[4][4] = {};
  for (int k0 = 0; k0 < K; k0 += 16) {
    float4 va = *(const float4*)(A + (size_t)(m0 + lm) * lda + k0 + lk);
    float4 vb = make_float4(0.f, 0.f, 0.f, 0.f);
    if (n0 + lm < N) vb = *(const float4*)(B + (size_t)(n0 + lm) * ldb + k0 + lk);
    __syncthreads();
    As[lk + 0][lm] = va.x; As[lk + 1][lm] = va.y;
    As[lk + 2][lm] = va.z; As[lk + 3][lm] = va.w;
    Bs[lk + 0][lm] = vb.x; Bs[lk + 1][lm] = vb.y;
    Bs[lk + 2][lm] = vb.z; Bs[lk + 3][lm] = vb.w;
    __syncthreads();
#pragma unroll
    for (int k = 0; k < 16; ++k) {
      float4 a = *(const float4*)&As[k][ty << 2];
      float4 b = *(const float4*)&Bs[k][tx << 2];
      float av[4] = {a.x, a.y, a.z, a.w};
      float bv[4] = {b.x, b.y, b.z, b.w};
#pragma unroll
      for (int i = 0; i < 4; ++i)
#pragma unroll
        for (int j = 0; j < 4; ++j)
          acc[i][j] += av[i] * bv[j];
    }
  }
#pragma unroll
  for (int i = 0; i < 4; ++i) {
    int row = m0 + (ty << 2) + i;
#pragma unroll
    for (int j = 0; j < 4; ++j) {
      int col = n0 + (tx << 2) + j;
      if (col < N) {
        float v = acc[i][j];
        if (EPI == 1) {
          v += extra[col];
          v = (v > 20.f) ? v : log1pf(expf(v));
        }
        if (EPI == 2) {
          v += extra[(size_t)row * lde + col];
        }
        C[(size_t)row * ldc + col] = v;
      }
    }
  }
}

// ---------------- causal depthwise conv (width 4) + bias + SiLU ----------------
__global__ void conv_silu_kernel(const float* __restrict__ xz,
                                 const float* __restrict__ conv_w,
                                 const float* __restrict__ conv_b,
                                 float* __restrict__ xconv) {
  int idx = blockIdx.x * blockDim.x + threadIdx.x;
  if (idx >= L_SEQ * DI) return;
  int d = idx & (DI - 1);
  int t = idx >> 11;
  float acc = conv_b[d];
  const float4 w = *(const float4*)(conv_w + (size_t)d * 4);
  float wv[4] = {w.x, w.y, w.z, w.w};
#pragma unroll
  for (int j = 0; j < 4; ++j) {
    int tt = t - 3 + j;
    if (tt >= 0) acc += xz[(size_t)tt * (2 * DI) + d] * wv[j];
  }
  xconv[idx] = acc / (1.f + expf(-acc));
}

// ---------------- chunked selective scan ----------------
// Pass A: per (d, n, chunk) compute P = prod(dA), HB = chunk-local scan end.
// Layout of P/HB/HIN: [chunk][d][n]  (256-contiguous per block write)
__global__ void scan_chunk_kernel(const float* __restrict__ delta,
                                  const float* __restrict__ u,
                                  const float* __restrict__ xdbl,
                                  const float* __restrict__ A_log,
                                  float* __restrict__ P,
                                  float* __restrict__ HB) {
  int lane = threadIdx.x & 15;
  int grp = threadIdx.x >> 4;
  int d = blockIdx.x * 16 + grp;
  int c = blockIdx.y;
  int t0 = c * TCH;
  float Aval = -expf(A_log[(size_t)d * DS + lane]);
  float p = 1.f, hb = 0.f;
#pragma unroll 4
  for (int t = t0; t < t0 + TCH; ++t) {
    float dlt = delta[(size_t)t * DI + d];
    float uv = u[(size_t)t * DI + d];
    float Bv = xdbl[(size_t)t * XDN + DR + lane];
    float dA = expf(dlt * Aval);
    p *= dA;
    hb = dA * hb + dlt * Bv * uv;
  }
  size_t idx = ((size_t)c * DI + d) * DS + lane;
  P[idx] = p;
  HB[idx] = hb;
}

// Pass B: propagate chunk carries; one thread per (d,n). Coalesced over dn.
__global__ void scan_prop_kernel(const float* __restrict__ P,
                                 const float* __restrict__ HB,
                                 float* __restrict__ HIN) {
  int dn = blockIdx.x * blockDim.x + threadIdx.x;
  float h = 0.f;
#pragma unroll 4
  for (int c = 0; c < NCHUNK; ++c) {
    size_t idx = (size_t)c * (DI * DS) + dn;
    HIN[idx] = h;
    h = P[idx] * h + HB[idx];
  }
}

// Pass C: redo local scan seeded with HIN; fuse C-contraction, D-skip, silu(z) gate.
__global__ void scan_final_kernel(const float* __restrict__ delta,
                                  const float* __restrict__ u,
                                  const float* __restrict__ xdbl,
                                  const float* __restrict__ xz,
                                  const float* __restrict__ A_log,
                                  const float* __restrict__ Dp,
                                  const float* __restrict__ HIN,
                                  float* __restrict__ yg) {
  int lane = threadIdx.x & 15;
  int grp = threadIdx.x >> 4;
  int d = blockIdx.x * 16 + grp;
  int c = blockIdx.y;
  int t0 = c * TCH;
  float Aval = -expf(A_log[(size_t)d * DS + lane]);
  float Dval = Dp[d];
  float h = HIN[((size_t)c * DI + d) * DS + lane];
#pragma unroll 2
  for (int t = t0; t < t0 + TCH; ++t) {
    float dlt = delta[(size_t)t * DI + d];
    float uv = u[(size_t)t * DI + d];
    float Bv = xdbl[(size_t)t * XDN + DR + lane];
    float Cv = xdbl[(size_t)t * XDN + DR + DS + lane];
    float dA = expf(dlt * Aval);
    h = dA * h + dlt * Bv * uv;
    float cacc = h * Cv;
#pragma unroll
    for (int off = 1; off < 16; off <<= 1) cacc += __shfl_xor(cacc, off, 16);
    if (lane == 0) {
      float y = cacc + uv * Dval;
      float z = xz[(size_t)t * (2 * DI) + DI + d];
      float sz = z / (1.f + expf(-z));
      yg[(size_t)t * DI + d] = y * sz;
    }
  }
}

extern "C" void kernel_launch(void* const* d_in, const int* in_sizes, int n_in,
                              void* d_out, int out_size, void* d_ws, size_t ws_size,
                              hipStream_t stream) {
  const float* x = (const float*)d_in[0];
  const float* gamma = (const float*)d_in[1];
  const float* beta = (const float*)d_in[2];
  const float* w_in = (const float*)d_in[3];
  const float* conv_w = (const float*)d_in[4];
  const float* conv_b = (const float*)d_in[5];
  const float* w_x = (const float*)d_in[6];
  const float* w_dt = (const float*)d_in[7];
  const float* b_dt = (const float*)d_in[8];
  const float* A_log = (const float*)d_in[9];
  const float* Dp = (const float*)d_in[10];
  const float* w_out = (const float*)d_in[11];
  float* out = (float*)d_out;

  float* ws = (float*)d_ws;
  float* xn = ws;                       // 2048*1024
  float* xz = xn + L_SEQ * DM;          // 2048*4096
  float* xconv = xz + L_SEQ * 2 * DI;   // 2048*2048
  float* xdbl = xconv + L_SEQ * DI;     // 2048*96
  float* delta = xdbl + L_SEQ * XDN;    // 2048*2048
  float* yg = delta + L_SEQ * DI;       // 2048*2048
  float* P = yg + L_SEQ * DI;           // 64*2048*16
  float* HB = P + NCHUNK * DI * DS;     // 64*2048*16
  float* HIN = HB + NCHUNK * DI * DS;   // 64*2048*16

  // 1. LayerNorm
  ln_kernel<<<L_SEQ, 256, 0, stream>>>(x, gamma, beta, xn);
  // 2. xz = xn @ w_in^T   (2048 x 4096, K=1024)
  gemm_bt<0><<<dim3((2 * DI) / 64, L_SEQ / 64), 256, 0, stream>>>(
      xn, DM, w_in, DM, xz, 2 * DI, L_SEQ, 2 * DI, DM, nullptr, 0);
  // 3. conv + silu -> xconv (2048 x 2048)
  conv_silu_kernel<<<(L_SEQ * DI) / 256, 256, 0, stream>>>(xz, conv_w, conv_b, xconv);
  // 4. x_dbl = xconv @ w_x^T  (2048 x 96, K=2048)
  gemm_bt<0><<<dim3((XDN + 63) / 64, L_SEQ / 64), 256, 0, stream>>>(
      xconv, DI, w_x, DI, xdbl, XDN, L_SEQ, XDN, DI, nullptr, 0);
  // 5. delta = softplus(dt @ w_dt^T + b_dt)  (2048 x 2048, K=64)
  gemm_bt<1><<<dim3(DI / 64, L_SEQ / 64), 256, 0, stream>>>(
      xdbl, XDN, w_dt, DR, delta, DI, L_SEQ, DI, DR, b_dt, 0);
  // 6. chunked selective scan + gate
  scan_chunk_kernel<<<dim3(DI / 16, NCHUNK), 256, 0, stream>>>(
      delta, xconv, xdbl, A_log, P, HB);
  scan_prop_kernel<<<(DI * DS) / 256, 256, 0, stream>>>(P, HB, HIN);
  scan_final_kernel<<<dim3(DI / 16, NCHUNK), 256, 0, stream>>>(
      delta, xconv, xdbl, xz, A_log, Dp, HIN, yg);
  // 7. out = yg @ w_out^T + residual  (2048 x 1024, K=2048)
  gemm_bt<2><<<dim3(DM / 64, L_SEQ / 64), 256, 0, stream>>>(
      yg, DI, w_out, DI, out, DM, L_SEQ, DM, DI, x, DM);
}

// Round 3
// 345.954 us; speedup vs baseline: 6.1920x; 1.9537x over previous
//
#include <hip/hip_runtime.h>
#include <math.h>

#define L_SEQ 2048
#define DM 1024      // D_MODEL
#define DI 2048      // D_INNER
#define DS 16        // D_STATE
#define DR 64        // DT_RANK
#define XDN 96       // DT_RANK + 2*D_STATE
#define NCHUNK 64
#define TCH 32       // L_SEQ / NCHUNK

typedef __attribute__((ext_vector_type(8))) short bf16x8;
typedef __attribute__((ext_vector_type(4))) float f32x4;
typedef unsigned short ushort_t;
typedef __attribute__((address_space(1))) const unsigned int GU32;
typedef __attribute__((address_space(3))) unsigned int LU32;

__device__ inline unsigned short f2bf(float f) {
  unsigned int u = __builtin_bit_cast(unsigned int, f);
  u += 0x7fffu + ((u >> 16) & 1u);  // round-to-nearest-even
  return (unsigned short)(u >> 16);
}

// ---------------- LayerNorm: one block per row, emits bf16 ----------------
__global__ void ln_kernel(const float* __restrict__ x,
                          const float* __restrict__ gamma,
                          const float* __restrict__ beta,
                          ushort_t* __restrict__ xnb) {
  int row = blockIdx.x;
  int t = threadIdx.x;
  const float4* xr = (const float4*)(x + (size_t)row * DM);
  float4 v = xr[t];
  float s = v.x + v.y + v.z + v.w;
  float s2 = v.x * v.x + v.y * v.y + v.z * v.z + v.w * v.w;
#pragma unroll
  for (int off = 32; off > 0; off >>= 1) {
    s += __shfl_down(s, off);
    s2 += __shfl_down(s2, off);
  }
  __shared__ float ls[4], ls2[4];
  if ((t & 63) == 0) { ls[t >> 6] = s; ls2[t >> 6] = s2; }
  __syncthreads();
  float tot = ls[0] + ls[1] + ls[2] + ls[3];
  float tot2 = ls2[0] + ls2[1] + ls2[2] + ls2[3];
  float mu = tot * (1.0f / DM);
  float var = tot2 * (1.0f / DM) - mu * mu;
  float r = rsqrtf(var + 1e-5f);
  float4 g = ((const float4*)gamma)[t];
  float4 b = ((const float4*)beta)[t];
  ushort4 o;
  o.x = f2bf((v.x - mu) * r * g.x + b.x);
  o.y = f2bf((v.y - mu) * r * g.y + b.y);
  o.z = f2bf((v.z - mu) * r * g.z + b.z);
  o.w = f2bf((v.w - mu) * r * g.w + b.w);
  ((ushort4*)(xnb + (size_t)row * DM))[t] = o;
}

// ---------------- fp32 -> bf16 converters ----------------
__global__ void cvt_bf16_kernel(const float* __restrict__ src,
                                ushort_t* __restrict__ dst, int n4) {
  int i = blockIdx.x * blockDim.x + threadIdx.x;
  if (i >= n4) return;
  float4 v = ((const float4*)src)[i];
  ushort4 o;
  o.x = f2bf(v.x); o.y = f2bf(v.y); o.z = f2bf(v.z); o.w = f2bf(v.w);
  ((ushort4*)dst)[i] = o;
}

// w_x [96][2048] -> padded bf16 [128][2048] (rows 96..127 zero)
__global__ void cvt_wx_kernel(const float* __restrict__ wx,
                              ushort_t* __restrict__ dst) {
  int i = blockIdx.x * blockDim.x + threadIdx.x;  // 128*2048/4 units
  int e0 = i << 2;
  int row = e0 >> 11;
  int col = e0 & (DI - 1);
  ushort4 o = {0, 0, 0, 0};
  if (row < XDN) {
    float4 v = *(const float4*)(wx + (size_t)row * DI + col);
    o.x = f2bf(v.x); o.y = f2bf(v.y); o.z = f2bf(v.z); o.w = f2bf(v.w);
  }
  ((ushort4*)dst)[i] = o;
}

// ---------------- bf16 MFMA GEMM: C[M,N](f32) = A[M,K] * B[N,K]^T ----------------
// m97 structure: 128x128 tile, BK=32, 4 waves (2x2), global_load_lds 16B,
// 2 barriers per K-step. EPI 0: plain; 2: +extra[row*lde+col]; 3: store if col<nvalid.
template <int EPI>
__global__ __launch_bounds__(256) void mgemm(
    const ushort_t* __restrict__ A, int lda,
    const ushort_t* __restrict__ B, int ldb,
    float* __restrict__ C, int ldc, int K,
    const float* __restrict__ extra, int lde, int nvalid) {
  __shared__ ushort_t As[128 * 32];
  __shared__ ushort_t Bs[128 * 32];
  const int tid = threadIdx.x;
  const int lane = tid & 63;
  const int wave = tid >> 6;
  const int m0 = blockIdx.y * 128;
  const int n0 = blockIdx.x * 128;
  const int wr = (wave >> 1) * 64;
  const int wc = (wave & 1) * 64;
  const int kq = lane >> 4;   // 0..3
  const int rr = lane & 15;
  f32x4 acc[4][4];
#pragma unroll
  for (int i = 0; i < 4; ++i)
#pragma unroll
    for (int j = 0; j < 4; ++j) acc[i][j] = (f32x4){0.f, 0.f, 0.f, 0.f};

  // staging: unit u (0..511) = 16B; row = u>>2, col = (u&3)*8 elems; LDS byte off = u*16
  const int u0 = tid, u1 = tid + 256;
  const int rA0 = u0 >> 2, cA0 = (u0 & 3) << 3;
  const int rA1 = u1 >> 2, cA1 = (u1 & 3) << 3;

  for (int k0 = 0; k0 < K; k0 += 32) {
    __syncthreads();
    __builtin_amdgcn_global_load_lds(
        (GU32*)(A + (size_t)(m0 + rA0) * lda + k0 + cA0),
        (LU32*)(As + u0 * 8), 16, 0, 0);
    __builtin_amdgcn_global_load_lds(
        (GU32*)(A + (size_t)(m0 + rA1) * lda + k0 + cA1),
        (LU32*)(As + u1 * 8), 16, 0, 0);
    __builtin_amdgcn_global_load_lds(
        (GU32*)(B + (size_t)(n0 + rA0) * ldb + k0 + cA0),
        (LU32*)(Bs + u0 * 8), 16, 0, 0);
    __builtin_amdgcn_global_load_lds(
        (GU32*)(B + (size_t)(n0 + rA1) * ldb + k0 + cA1),
        (LU32*)(Bs + u1 * 8), 16, 0, 0);
    __syncthreads();
    bf16x8 a[4], b[4];
#pragma unroll
    for (int i = 0; i < 4; ++i)
      a[i] = *(const bf16x8*)(As + (wr + i * 16 + rr) * 32 + kq * 8);
#pragma unroll
    for (int j = 0; j < 4; ++j)
      b[j] = *(const bf16x8*)(Bs + (wc + j * 16 + rr) * 32 + kq * 8);
#pragma unroll
    for (int i = 0; i < 4; ++i)
#pragma unroll
      for (int j = 0; j < 4; ++j)
        acc[i][j] = __builtin_amdgcn_mfma_f32_16x16x32_bf16(a[i], b[j], acc[i][j], 0, 0, 0);
  }
  // epilogue: C/D layout col=lane&15, row=(lane>>4)*4+reg  [m89/m91 verified]
#pragma unroll
  for (int i = 0; i < 4; ++i) {
#pragma unroll
    for (int j = 0; j < 4; ++j) {
#pragma unroll
      for (int r = 0; r < 4; ++r) {
        int row = m0 + wr + i * 16 + kq * 4 + r;
        int col = n0 + wc + j * 16 + rr;
        float v = acc[i][j][r];
        if (EPI == 2) v += extra[(size_t)row * lde + col];
        if (EPI == 3) {
          if (col < nvalid) C[(size_t)row * ldc + col] = v;
        } else {
          C[(size_t)row * ldc + col] = v;
        }
      }
    }
  }
}

// ---------------- fp32 GEMM (small): C = A*B^T, EPI1 = softplus(+bias) ----------------
template <int EPI>
__global__ void gemm_bt(const float* __restrict__ A, int lda,
                        const float* __restrict__ B, int ldb,
                        float* __restrict__ C, int ldc,
                        int M, int N, int K,
                        const float* __restrict__ extra, int lde) {
  __shared__ float As[16][68];
  __shared__ float Bs[16][68];
  const int tid = threadIdx.x;
  const int tx = tid & 15;
  const int ty = tid >> 4;
  const int m0 = blockIdx.y * 64;
  const int n0 = blockIdx.x * 64;
  const int lm = tid >> 2;
  const int lk = (tid & 3) << 2;
  float acc[4][4] = {};
  for (int k0 = 0; k0 < K; k0 += 16) {
    float4 va = *(const float4*)(A + (size_t)(m0 + lm) * lda + k0 + lk);
    float4 vb = make_float4(0.f, 0.f, 0.f, 0.f);
    if (n0 + lm < N) vb = *(const float4*)(B + (size_t)(n0 + lm) * ldb + k0 + lk);
    __syncthreads();
    As[lk + 0][lm] = va.x; As[lk + 1][lm] = va.y;
    As[lk + 2][lm] = va.z; As[lk + 3][lm] = va.w;
    Bs[lk + 0][lm] = vb.x; Bs[lk + 1][lm] = vb.y;
    Bs[lk + 2][lm] = vb.z; Bs[lk + 3][lm] = vb.w;
    __syncthreads();
#pragma unroll
    for (int k = 0; k < 16; ++k) {
      float4 a = *(const float4*)&As[k][ty << 2];
      float4 b = *(const float4*)&Bs[k][tx << 2];
      float av[4] = {a.x, a.y, a.z, a.w};
      float bv[4] = {b.x, b.y, b.z, b.w};
#pragma unroll
      for (int i = 0; i < 4; ++i)
#pragma unroll
        for (int j = 0; j < 4; ++j)
          acc[i][j] += av[i] * bv[j];
    }
  }
#pragma unroll
  for (int i = 0; i < 4; ++i) {
    int row = m0 + (ty << 2) + i;
#pragma unroll
    for (int j = 0; j < 4; ++j) {
      int col = n0 + (tx << 2) + j;
      if (col < N) {
        float v = acc[i][j];
        if (EPI == 1) {
          v += extra[col];
          v = (v > 20.f) ? v : log1pf(expf(v));
        }
        C[(size_t)row * ldc + col] = v;
      }
    }
  }
}

// ---------------- causal depthwise conv (width 4) + bias + SiLU ----------------
__global__ void conv_silu_kernel(const float* __restrict__ xz,
                                 const float* __restrict__ conv_w,
                                 const float* __restrict__ conv_b,
                                 float* __restrict__ xconv,
                                 ushort_t* __restrict__ xconvb) {
  int idx = blockIdx.x * blockDim.x + threadIdx.x;
  if (idx >= L_SEQ * DI) return;
  int d = idx & (DI - 1);
  int t = idx >> 11;
  float acc = conv_b[d];
  const float4 w = *(const float4*)(conv_w + (size_t)d * 4);
  float wv[4] = {w.x, w.y, w.z, w.w};
#pragma unroll
  for (int j = 0; j < 4; ++j) {
    int tt = t - 3 + j;
    if (tt >= 0) acc += xz[(size_t)tt * (2 * DI) + d] * wv[j];
  }
  float r = acc / (1.f + expf(-acc));
  xconv[idx] = r;
  xconvb[idx] = f2bf(r);
}

// ---------------- chunked selective scan ----------------
__global__ void scan_chunk_kernel(const float* __restrict__ delta,
                                  const float* __restrict__ u,
                                  const float* __restrict__ xdbl,
                                  const float* __restrict__ A_log,
                                  float* __restrict__ P,
                                  float* __restrict__ HB) {
  int lane = threadIdx.x & 15;
  int grp = threadIdx.x >> 4;
  int d = blockIdx.x * 16 + grp;
  int c = blockIdx.y;
  int t0 = c * TCH;
  float Aval = -expf(A_log[(size_t)d * DS + lane]);
  float p = 1.f, hb = 0.f;
#pragma unroll 4
  for (int t = t0; t < t0 + TCH; ++t) {
    float dlt = delta[(size_t)t * DI + d];
    float uv = u[(size_t)t * DI + d];
    float Bv = xdbl[(size_t)t * XDN + DR + lane];
    float dA = expf(dlt * Aval);
    p *= dA;
    hb = dA * hb + dlt * Bv * uv;
  }
  size_t idx = ((size_t)c * DI + d) * DS + lane;
  P[idx] = p;
  HB[idx] = hb;
}

__global__ void scan_prop_kernel(const float* __restrict__ P,
                                 const float* __restrict__ HB,
                                 float* __restrict__ HIN) {
  int dn = blockIdx.x * blockDim.x + threadIdx.x;
  float h = 0.f;
#pragma unroll 4
  for (int c = 0; c < NCHUNK; ++c) {
    size_t idx = (size_t)c * (DI * DS) + dn;
    HIN[idx] = h;
    h = P[idx] * h + HB[idx];
  }
}

__global__ void scan_final_kernel(const float* __restrict__ delta,
                                  const float* __restrict__ u,
                                  const float* __restrict__ xdbl,
                                  const float* __restrict__ xz,
                                  const float* __restrict__ A_log,
                                  const float* __restrict__ Dp,
                                  const float* __restrict__ HIN,
                                  ushort_t* __restrict__ ygb) {
  int lane = threadIdx.x & 15;
  int grp = threadIdx.x >> 4;
  int d = blockIdx.x * 16 + grp;
  int c = blockIdx.y;
  int t0 = c * TCH;
  float Aval = -expf(A_log[(size_t)d * DS + lane]);
  float Dval = Dp[d];
  float h = HIN[((size_t)c * DI + d) * DS + lane];
#pragma unroll 2
  for (int t = t0; t < t0 + TCH; ++t) {
    float dlt = delta[(size_t)t * DI + d];
    float uv = u[(size_t)t * DI + d];
    float Bv = xdbl[(size_t)t * XDN + DR + lane];
    float Cv = xdbl[(size_t)t * XDN + DR + DS + lane];
    float dA = expf(dlt * Aval);
    h = dA * h + dlt * Bv * uv;
    float cacc = h * Cv;
#pragma unroll
    for (int off = 1; off < 16; off <<= 1) cacc += __shfl_xor(cacc, off, 16);
    if (lane == 0) {
      float y = cacc + uv * Dval;
      float z = xz[(size_t)t * (2 * DI) + DI + d];
      float sz = z / (1.f + expf(-z));
      ygb[(size_t)t * DI + d] = f2bf(y * sz);
    }
  }
}

extern "C" void kernel_launch(void* const* d_in, const int* in_sizes, int n_in,
                              void* d_out, int out_size, void* d_ws, size_t ws_size,
                              hipStream_t stream) {
  const float* x = (const float*)d_in[0];
  const float* gamma = (const float*)d_in[1];
  const float* beta = (const float*)d_in[2];
  const float* w_in = (const float*)d_in[3];
  const float* conv_w = (const float*)d_in[4];
  const float* conv_b = (const float*)d_in[5];
  const float* w_x = (const float*)d_in[6];
  const float* w_dt = (const float*)d_in[7];
  const float* b_dt = (const float*)d_in[8];
  const float* A_log = (const float*)d_in[9];
  const float* Dp = (const float*)d_in[10];
  const float* w_out = (const float*)d_in[11];
  float* out = (float*)d_out;

  float* ws = (float*)d_ws;
  float* xz = ws;                              // 2048*4096
  float* xconv = xz + (size_t)L_SEQ * 2 * DI;  // 2048*2048
  float* xdbl = xconv + (size_t)L_SEQ * DI;    // 2048*96
  float* delta = xdbl + (size_t)L_SEQ * XDN;   // 2048*2048
  float* P = delta + (size_t)L_SEQ * DI;       // 64*2048*16
  float* HB = P + (size_t)NCHUNK * DI * DS;
  float* HIN = HB + (size_t)NCHUNK * DI * DS;
  ushort_t* xnb = (ushort_t*)(HIN + (size_t)NCHUNK * DI * DS);  // 2048*1024
  ushort_t* w_inb = xnb + (size_t)L_SEQ * DM;        // 4096*1024
  ushort_t* w_outb = w_inb + (size_t)(2 * DI) * DM;  // 1024*2048
  ushort_t* w_xb = w_outb + (size_t)DM * DI;         // 128*2048
  ushort_t* xconvb = w_xb + (size_t)128 * DI;        // 2048*2048
  ushort_t* ygb = xconvb + (size_t)L_SEQ * DI;       // 2048*2048

  // weight conversions
  cvt_bf16_kernel<<<(2 * DI * DM / 4) / 256, 256, 0, stream>>>(w_in, w_inb, 2 * DI * DM / 4);
  cvt_bf16_kernel<<<(DM * DI / 4) / 256, 256, 0, stream>>>(w_out, w_outb, DM * DI / 4);
  cvt_wx_kernel<<<(128 * DI / 4) / 256, 256, 0, stream>>>(w_x, w_xb);

  // 1. LayerNorm -> bf16
  ln_kernel<<<L_SEQ, 256, 0, stream>>>(x, gamma, beta, xnb);
  // 2. xz = xn @ w_in^T   (2048 x 4096, K=1024)  [bf16 MFMA]
  mgemm<0><<<dim3((2 * DI) / 128, L_SEQ / 128), 256, 0, stream>>>(
      xnb, DM, w_inb, DM, xz, 2 * DI, DM, nullptr, 0, 0);
  // 3. conv + silu -> xconv (f32) + xconvb (bf16)
  conv_silu_kernel<<<(L_SEQ * DI) / 256, 256, 0, stream>>>(xz, conv_w, conv_b, xconv, xconvb);
  // 4. x_dbl = xconv @ w_x^T  (2048 x 96, K=2048)  [bf16 MFMA, N padded to 128]
  mgemm<3><<<dim3(1, L_SEQ / 128), 256, 0, stream>>>(
      xconvb, DI, w_xb, DI, xdbl, XDN, DI, nullptr, 0, XDN);
  // 5. delta = softplus(dt @ w_dt^T + b_dt)  (2048 x 2048, K=64)  [fp32]
  gemm_bt<1><<<dim3(DI / 64, L_SEQ / 64), 256, 0, stream>>>(
      xdbl, XDN, w_dt, DR, delta, DI, L_SEQ, DI, DR, b_dt, 0);
  // 6. chunked selective scan + gate -> ygb (bf16)
  scan_chunk_kernel<<<dim3(DI / 16, NCHUNK), 256, 0, stream>>>(
      delta, xconv, xdbl, A_log, P, HB);
  scan_prop_kernel<<<(DI * DS) / 256, 256, 0, stream>>>(P, HB, HIN);
  scan_final_kernel<<<dim3(DI / 16, NCHUNK), 256, 0, stream>>>(
      delta, xconv, xdbl, xz, A_log, Dp, HIN, ygb);
  // 7. out = yg @ w_out^T + residual  (2048 x 1024, K=2048)  [bf16 MFMA]
  mgemm<2><<<dim3(DM / 128, L_SEQ / 128), 256, 0, stream>>>(
      ygb, DI, w_outb, DI, out, DM, DI, x, DM, 0);
}

// Round 4
// 223.200 us; speedup vs baseline: 9.5975x; 1.5500x over previous
//
#include <hip/hip_runtime.h>
#include <math.h>

#define L_SEQ 2048
#define DM 1024      // D_MODEL
#define DI 2048      // D_INNER
#define DS 16        // D_STATE
#define DR 64        // DT_RANK
#define XDN 96       // DT_RANK + 2*D_STATE
#define NCHUNK 64
#define TCH 32       // L_SEQ / NCHUNK

typedef __attribute__((ext_vector_type(8))) short bf16x8;
typedef __attribute__((ext_vector_type(4))) float f32x4;
typedef unsigned short ushort_t;
typedef __attribute__((address_space(1))) const unsigned int GU32;
typedef __attribute__((address_space(3))) unsigned int LU32;

__device__ inline unsigned short f2bf(float f) {
  unsigned int u = __builtin_bit_cast(unsigned int, f);
  u += 0x7fffu + ((u >> 16) & 1u);  // round-to-nearest-even
  return (unsigned short)(u >> 16);
}

// ---------------- LayerNorm: one block per row, emits bf16 ----------------
__global__ void ln_kernel(const float* __restrict__ x,
                          const float* __restrict__ gamma,
                          const float* __restrict__ beta,
                          ushort_t* __restrict__ xnb) {
  int row = blockIdx.x;
  int t = threadIdx.x;
  const float4* xr = (const float4*)(x + (size_t)row * DM);
  float4 v = xr[t];
  float s = v.x + v.y + v.z + v.w;
  float s2 = v.x * v.x + v.y * v.y + v.z * v.z + v.w * v.w;
#pragma unroll
  for (int off = 32; off > 0; off >>= 1) {
    s += __shfl_down(s, off);
    s2 += __shfl_down(s2, off);
  }
  __shared__ float ls[4], ls2[4];
  if ((t & 63) == 0) { ls[t >> 6] = s; ls2[t >> 6] = s2; }
  __syncthreads();
  float tot = ls[0] + ls[1] + ls[2] + ls[3];
  float tot2 = ls2[0] + ls2[1] + ls2[2] + ls2[3];
  float mu = tot * (1.0f / DM);
  float var = tot2 * (1.0f / DM) - mu * mu;
  float r = rsqrtf(var + 1e-5f);
  float4 g = ((const float4*)gamma)[t];
  float4 b = ((const float4*)beta)[t];
  ushort4 o;
  o.x = f2bf((v.x - mu) * r * g.x + b.x);
  o.y = f2bf((v.y - mu) * r * g.y + b.y);
  o.z = f2bf((v.z - mu) * r * g.z + b.z);
  o.w = f2bf((v.w - mu) * r * g.w + b.w);
  ((ushort4*)(xnb + (size_t)row * DM))[t] = o;
}

// ---------------- fp32 -> bf16 converters ----------------
__global__ void cvt_bf16_kernel(const float* __restrict__ src,
                                ushort_t* __restrict__ dst, int n4) {
  int i = blockIdx.x * blockDim.x + threadIdx.x;
  if (i >= n4) return;
  float4 v = ((const float4*)src)[i];
  ushort4 o;
  o.x = f2bf(v.x); o.y = f2bf(v.y); o.z = f2bf(v.z); o.w = f2bf(v.w);
  ((ushort4*)dst)[i] = o;
}

// w_x [96][2048] -> padded bf16 [128][2048] (rows 96..127 zero)
__global__ void cvt_wx_kernel(const float* __restrict__ wx,
                              ushort_t* __restrict__ dst) {
  int i = blockIdx.x * blockDim.x + threadIdx.x;
  int e0 = i << 2;
  int row = e0 >> 11;
  int col = e0 & (DI - 1);
  ushort4 o = {0, 0, 0, 0};
  if (row < XDN) {
    float4 v = *(const float4*)(wx + (size_t)row * DI + col);
    o.x = f2bf(v.x); o.y = f2bf(v.y); o.z = f2bf(v.z); o.w = f2bf(v.w);
  }
  ((ushort4*)dst)[i] = o;
}

// ---------------- bf16 MFMA GEMM: C[M,N](f32) = A[M,K] * B[N,K]^T ----------------
template <int EPI>
__global__ __launch_bounds__(256) void mgemm(
    const ushort_t* __restrict__ A, int lda,
    const ushort_t* __restrict__ B, int ldb,
    float* __restrict__ C, int ldc, int K,
    const float* __restrict__ extra, int lde, int nvalid) {
  __shared__ ushort_t As[128 * 32];
  __shared__ ushort_t Bs[128 * 32];
  const int tid = threadIdx.x;
  const int lane = tid & 63;
  const int wave = tid >> 6;
  const int m0 = blockIdx.y * 128;
  const int n0 = blockIdx.x * 128;
  const int wr = (wave >> 1) * 64;
  const int wc = (wave & 1) * 64;
  const int kq = lane >> 4;
  const int rr = lane & 15;
  f32x4 acc[4][4];
#pragma unroll
  for (int i = 0; i < 4; ++i)
#pragma unroll
    for (int j = 0; j < 4; ++j) acc[i][j] = (f32x4){0.f, 0.f, 0.f, 0.f};

  const int u0 = tid, u1 = tid + 256;
  const int rA0 = u0 >> 2, cA0 = (u0 & 3) << 3;
  const int rA1 = u1 >> 2, cA1 = (u1 & 3) << 3;

  for (int k0 = 0; k0 < K; k0 += 32) {
    __syncthreads();
    __builtin_amdgcn_global_load_lds(
        (GU32*)(A + (size_t)(m0 + rA0) * lda + k0 + cA0),
        (LU32*)(As + u0 * 8), 16, 0, 0);
    __builtin_amdgcn_global_load_lds(
        (GU32*)(A + (size_t)(m0 + rA1) * lda + k0 + cA1),
        (LU32*)(As + u1 * 8), 16, 0, 0);
    __builtin_amdgcn_global_load_lds(
        (GU32*)(B + (size_t)(n0 + rA0) * ldb + k0 + cA0),
        (LU32*)(Bs + u0 * 8), 16, 0, 0);
    __builtin_amdgcn_global_load_lds(
        (GU32*)(B + (size_t)(n0 + rA1) * ldb + k0 + cA1),
        (LU32*)(Bs + u1 * 8), 16, 0, 0);
    __syncthreads();
    bf16x8 a[4], b[4];
#pragma unroll
    for (int i = 0; i < 4; ++i)
      a[i] = *(const bf16x8*)(As + (wr + i * 16 + rr) * 32 + kq * 8);
#pragma unroll
    for (int j = 0; j < 4; ++j)
      b[j] = *(const bf16x8*)(Bs + (wc + j * 16 + rr) * 32 + kq * 8);
#pragma unroll
    for (int i = 0; i < 4; ++i)
#pragma unroll
      for (int j = 0; j < 4; ++j)
        acc[i][j] = __builtin_amdgcn_mfma_f32_16x16x32_bf16(a[i], b[j], acc[i][j], 0, 0, 0);
  }
#pragma unroll
  for (int i = 0; i < 4; ++i) {
#pragma unroll
    for (int j = 0; j < 4; ++j) {
#pragma unroll
      for (int r = 0; r < 4; ++r) {
        int row = m0 + wr + i * 16 + kq * 4 + r;
        int col = n0 + wc + j * 16 + rr;
        float v = acc[i][j][r];
        if (EPI == 2) v += extra[(size_t)row * lde + col];
        if (EPI == 3) {
          if (col < nvalid) C[(size_t)row * ldc + col] = v;
        } else {
          C[(size_t)row * ldc + col] = v;
        }
      }
    }
  }
}

// ---------------- fp32 GEMM (small): C = A*B^T, EPI1 = softplus(+bias) ----------------
template <int EPI>
__global__ void gemm_bt(const float* __restrict__ A, int lda,
                        const float* __restrict__ B, int ldb,
                        float* __restrict__ C, int ldc,
                        int M, int N, int K,
                        const float* __restrict__ extra, int lde) {
  __shared__ float As[16][68];
  __shared__ float Bs[16][68];
  const int tid = threadIdx.x;
  const int tx = tid & 15;
  const int ty = tid >> 4;
  const int m0 = blockIdx.y * 64;
  const int n0 = blockIdx.x * 64;
  const int lm = tid >> 2;
  const int lk = (tid & 3) << 2;
  float acc[4][4] = {};
  for (int k0 = 0; k0 < K; k0 += 16) {
    float4 va = *(const float4*)(A + (size_t)(m0 + lm) * lda + k0 + lk);
    float4 vb = make_float4(0.f, 0.f, 0.f, 0.f);
    if (n0 + lm < N) vb = *(const float4*)(B + (size_t)(n0 + lm) * ldb + k0 + lk);
    __syncthreads();
    As[lk + 0][lm] = va.x; As[lk + 1][lm] = va.y;
    As[lk + 2][lm] = va.z; As[lk + 3][lm] = va.w;
    Bs[lk + 0][lm] = vb.x; Bs[lk + 1][lm] = vb.y;
    Bs[lk + 2][lm] = vb.z; Bs[lk + 3][lm] = vb.w;
    __syncthreads();
#pragma unroll
    for (int k = 0; k < 16; ++k) {
      float4 a = *(const float4*)&As[k][ty << 2];
      float4 b = *(const float4*)&Bs[k][tx << 2];
      float av[4] = {a.x, a.y, a.z, a.w};
      float bv[4] = {b.x, b.y, b.z, b.w};
#pragma unroll
      for (int i = 0; i < 4; ++i)
#pragma unroll
        for (int j = 0; j < 4; ++j)
          acc[i][j] += av[i] * bv[j];
    }
  }
#pragma unroll
  for (int i = 0; i < 4; ++i) {
    int row = m0 + (ty << 2) + i;
#pragma unroll
    for (int j = 0; j < 4; ++j) {
      int col = n0 + (tx << 2) + j;
      if (col < N) {
        float v = acc[i][j];
        if (EPI == 1) {
          v += extra[col];
          v = (v > 20.f) ? v : __logf(1.f + __expf(v));
        }
        C[(size_t)row * ldc + col] = v;
      }
    }
  }
}

// ---------------- causal depthwise conv (width 4) + bias + SiLU ----------------
__global__ void conv_silu_kernel(const float* __restrict__ xz,
                                 const float* __restrict__ conv_w,
                                 const float* __restrict__ conv_b,
                                 float* __restrict__ xconv,
                                 ushort_t* __restrict__ xconvb) {
  int idx = blockIdx.x * blockDim.x + threadIdx.x;
  if (idx >= L_SEQ * DI) return;
  int d = idx & (DI - 1);
  int t = idx >> 11;
  float acc = conv_b[d];
  const float4 w = *(const float4*)(conv_w + (size_t)d * 4);
  float wv[4] = {w.x, w.y, w.z, w.w};
#pragma unroll
  for (int j = 0; j < 4; ++j) {
    int tt = t - 3 + j;
    if (tt >= 0) acc += xz[(size_t)tt * (2 * DI) + d] * wv[j];
  }
  float r = acc / (1.f + __expf(-acc));
  xconv[idx] = r;
  xconvb[idx] = f2bf(r);
}

// ---------------- chunked selective scan: one thread per channel d ----------------
// State h[16] (and p[16]) in registers. B/C rows wave-uniform broadcast loads.
// Carry layout: [chunk][n][d] -> flat idx = (c*DS + n)*DI + d (coalesced over d).
__global__ void scan_chunk_kernel(const float* __restrict__ delta,
                                  const float* __restrict__ u,
                                  const float* __restrict__ xdbl,
                                  const float* __restrict__ A_log,
                                  float* __restrict__ P,
                                  float* __restrict__ HB) {
  int d = blockIdx.x * blockDim.x + threadIdx.x;
  int c = blockIdx.y;
  int t0 = c * TCH;
  float Aval[DS];
#pragma unroll
  for (int q = 0; q < 4; ++q) {
    float4 al = *(const float4*)(A_log + (size_t)d * DS + q * 4);
    Aval[q * 4 + 0] = -__expf(al.x);
    Aval[q * 4 + 1] = -__expf(al.y);
    Aval[q * 4 + 2] = -__expf(al.z);
    Aval[q * 4 + 3] = -__expf(al.w);
  }
  float h[DS], p[DS];
#pragma unroll
  for (int n = 0; n < DS; ++n) { h[n] = 0.f; p[n] = 1.f; }
  for (int t = t0; t < t0 + TCH; ++t) {
    float dlt = delta[(size_t)t * DI + d];
    float uv = u[(size_t)t * DI + d];
    float du = dlt * uv;
    float Bv[DS];
#pragma unroll
    for (int q = 0; q < 4; ++q) {
      float4 b4 = *(const float4*)(xdbl + (size_t)t * XDN + DR + q * 4);
      Bv[q * 4 + 0] = b4.x; Bv[q * 4 + 1] = b4.y;
      Bv[q * 4 + 2] = b4.z; Bv[q * 4 + 3] = b4.w;
    }
#pragma unroll
    for (int n = 0; n < DS; ++n) {
      float dA = __expf(dlt * Aval[n]);
      p[n] *= dA;
      h[n] = dA * h[n] + du * Bv[n];
    }
  }
#pragma unroll
  for (int n = 0; n < DS; ++n) {
    size_t idx = ((size_t)c * DS + n) * DI + d;
    P[idx] = p[n];
    HB[idx] = h[n];
  }
}

// Pass B: propagate chunk carries; one thread per (n,d) flat index. Coalesced.
__global__ void scan_prop_kernel(const float* __restrict__ P,
                                 const float* __restrict__ HB,
                                 float* __restrict__ HIN) {
  int dn = blockIdx.x * blockDim.x + threadIdx.x;
  float h = 0.f;
#pragma unroll 4
  for (int c = 0; c < NCHUNK; ++c) {
    size_t idx = (size_t)c * (DI * DS) + dn;
    HIN[idx] = h;
    h = P[idx] * h + HB[idx];
  }
}

// Pass C: redo local scan seeded with HIN; fuse C-contraction, D-skip, silu(z) gate.
__global__ void scan_final_kernel(const float* __restrict__ delta,
                                  const float* __restrict__ u,
                                  const float* __restrict__ xdbl,
                                  const float* __restrict__ xz,
                                  const float* __restrict__ A_log,
                                  const float* __restrict__ Dp,
                                  const float* __restrict__ HIN,
                                  ushort_t* __restrict__ ygb) {
  int d = blockIdx.x * blockDim.x + threadIdx.x;
  int c = blockIdx.y;
  int t0 = c * TCH;
  float Aval[DS];
#pragma unroll
  for (int q = 0; q < 4; ++q) {
    float4 al = *(const float4*)(A_log + (size_t)d * DS + q * 4);
    Aval[q * 4 + 0] = -__expf(al.x);
    Aval[q * 4 + 1] = -__expf(al.y);
    Aval[q * 4 + 2] = -__expf(al.z);
    Aval[q * 4 + 3] = -__expf(al.w);
  }
  float Dval = Dp[d];
  float h[DS];
#pragma unroll
  for (int n = 0; n < DS; ++n) h[n] = HIN[((size_t)c * DS + n) * DI + d];
  for (int t = t0; t < t0 + TCH; ++t) {
    float dlt = delta[(size_t)t * DI + d];
    float uv = u[(size_t)t * DI + d];
    float du = dlt * uv;
    float Bv[DS], Cv[DS];
#pragma unroll
    for (int q = 0; q < 4; ++q) {
      float4 b4 = *(const float4*)(xdbl + (size_t)t * XDN + DR + q * 4);
      float4 c4 = *(const float4*)(xdbl + (size_t)t * XDN + DR + DS + q * 4);
      Bv[q * 4 + 0] = b4.x; Bv[q * 4 + 1] = b4.y;
      Bv[q * 4 + 2] = b4.z; Bv[q * 4 + 3] = b4.w;
      Cv[q * 4 + 0] = c4.x; Cv[q * 4 + 1] = c4.y;
      Cv[q * 4 + 2] = c4.z; Cv[q * 4 + 3] = c4.w;
    }
    float acc = uv * Dval;
#pragma unroll
    for (int n = 0; n < DS; ++n) {
      float dA = __expf(dlt * Aval[n]);
      h[n] = dA * h[n] + du * Bv[n];
      acc += h[n] * Cv[n];
    }
    float z = xz[(size_t)t * (2 * DI) + DI + d];
    float sz = z / (1.f + __expf(-z));
    ygb[(size_t)t * DI + d] = f2bf(acc * sz);
  }
}

extern "C" void kernel_launch(void* const* d_in, const int* in_sizes, int n_in,
                              void* d_out, int out_size, void* d_ws, size_t ws_size,
                              hipStream_t stream) {
  const float* x = (const float*)d_in[0];
  const float* gamma = (const float*)d_in[1];
  const float* beta = (const float*)d_in[2];
  const float* w_in = (const float*)d_in[3];
  const float* conv_w = (const float*)d_in[4];
  const float* conv_b = (const float*)d_in[5];
  const float* w_x = (const float*)d_in[6];
  const float* w_dt = (const float*)d_in[7];
  const float* b_dt = (const float*)d_in[8];
  const float* A_log = (const float*)d_in[9];
  const float* Dp = (const float*)d_in[10];
  const float* w_out = (const float*)d_in[11];
  float* out = (float*)d_out;

  float* ws = (float*)d_ws;
  float* xz = ws;                              // 2048*4096
  float* xconv = xz + (size_t)L_SEQ * 2 * DI;  // 2048*2048
  float* xdbl = xconv + (size_t)L_SEQ * DI;    // 2048*96
  float* delta = xdbl + (size_t)L_SEQ * XDN;   // 2048*2048
  float* P = delta + (size_t)L_SEQ * DI;       // 64*16*2048
  float* HB = P + (size_t)NCHUNK * DI * DS;
  float* HIN = HB + (size_t)NCHUNK * DI * DS;
  ushort_t* xnb = (ushort_t*)(HIN + (size_t)NCHUNK * DI * DS);  // 2048*1024
  ushort_t* w_inb = xnb + (size_t)L_SEQ * DM;        // 4096*1024
  ushort_t* w_outb = w_inb + (size_t)(2 * DI) * DM;  // 1024*2048
  ushort_t* w_xb = w_outb + (size_t)DM * DI;         // 128*2048
  ushort_t* xconvb = w_xb + (size_t)128 * DI;        // 2048*2048
  ushort_t* ygb = xconvb + (size_t)L_SEQ * DI;       // 2048*2048

  // weight conversions
  cvt_bf16_kernel<<<(2 * DI * DM / 4) / 256, 256, 0, stream>>>(w_in, w_inb, 2 * DI * DM / 4);
  cvt_bf16_kernel<<<(DM * DI / 4) / 256, 256, 0, stream>>>(w_out, w_outb, DM * DI / 4);
  cvt_wx_kernel<<<(128 * DI / 4) / 256, 256, 0, stream>>>(w_x, w_xb);

  // 1. LayerNorm -> bf16
  ln_kernel<<<L_SEQ, 256, 0, stream>>>(x, gamma, beta, xnb);
  // 2. xz = xn @ w_in^T   (2048 x 4096, K=1024)  [bf16 MFMA]
  mgemm<0><<<dim3((2 * DI) / 128, L_SEQ / 128), 256, 0, stream>>>(
      xnb, DM, w_inb, DM, xz, 2 * DI, DM, nullptr, 0, 0);
  // 3. conv + silu -> xconv (f32) + xconvb (bf16)
  conv_silu_kernel<<<(L_SEQ * DI) / 256, 256, 0, stream>>>(xz, conv_w, conv_b, xconv, xconvb);
  // 4. x_dbl = xconv @ w_x^T  (2048 x 96, K=2048)  [bf16 MFMA, N padded to 128]
  mgemm<3><<<dim3(1, L_SEQ / 128), 256, 0, stream>>>(
      xconvb, DI, w_xb, DI, xdbl, XDN, DI, nullptr, 0, XDN);
  // 5. delta = softplus(dt @ w_dt^T + b_dt)  (2048 x 2048, K=64)  [fp32]
  gemm_bt<1><<<dim3(DI / 64, L_SEQ / 64), 256, 0, stream>>>(
      xdbl, XDN, w_dt, DR, delta, DI, L_SEQ, DI, DR, b_dt, 0);
  // 6. chunked selective scan + gate -> ygb (bf16)
  scan_chunk_kernel<<<dim3(DI / 256, NCHUNK), 256, 0, stream>>>(
      delta, xconv, xdbl, A_log, P, HB);
  scan_prop_kernel<<<(DI * DS) / 256, 256, 0, stream>>>(P, HB, HIN);
  scan_final_kernel<<<dim3(DI / 256, NCHUNK), 256, 0, stream>>>(
      delta, xconv, xdbl, xz, A_log, Dp, HIN, ygb);
  // 7. out = yg @ w_out^T + residual  (2048 x 1024, K=2048)  [bf16 MFMA]
  mgemm<2><<<dim3(DM / 128, L_SEQ / 128), 256, 0, stream>>>(
      ygb, DI, w_outb, DI, out, DM, DI, x, DM, 0);
}

// Round 5
// 180.331 us; speedup vs baseline: 11.8790x; 1.2377x over previous
//
#include <hip/hip_runtime.h>
#include <math.h>

#define L_SEQ 2048
#define DM 1024      // D_MODEL
#define DI 2048      // D_INNER
#define DS 16        // D_STATE
#define DR 64        // DT_RANK
#define XDN 96       // DT_RANK + 2*D_STATE
#define NCHUNK 64
#define TCH 32       // L_SEQ / NCHUNK
#define KSLICES 8
#define KSL (DI / KSLICES)   // 256

typedef __attribute__((ext_vector_type(8))) short bf16x8;
typedef __attribute__((ext_vector_type(4))) float f32x4;
typedef unsigned short ushort_t;
typedef __attribute__((address_space(1))) const unsigned int GU32;
typedef __attribute__((address_space(3))) unsigned int LU32;

__device__ inline unsigned short f2bf(float f) {
  unsigned int u = __builtin_bit_cast(unsigned int, f);
  u += 0x7fffu + ((u >> 16) & 1u);  // round-to-nearest-even
  return (unsigned short)(u >> 16);
}
__device__ inline float bf2f(unsigned short u) {
  return __builtin_bit_cast(float, (unsigned int)u << 16);
}

// ---------------- fused weight conversion (one launch) ----------------
__device__ inline void cvt4(const float* src, ushort_t* dst, int j) {
  float4 v = ((const float4*)src)[j];
  ushort4 o;
  o.x = f2bf(v.x); o.y = f2bf(v.y); o.z = f2bf(v.z); o.w = f2bf(v.w);
  ((ushort4*)dst)[j] = o;
}

__global__ void cvt_all_kernel(const float* __restrict__ w_in,
                               const float* __restrict__ w_out,
                               const float* __restrict__ w_x,
                               const float* __restrict__ w_dt,
                               ushort_t* __restrict__ w_inb,
                               ushort_t* __restrict__ w_outb,
                               ushort_t* __restrict__ w_xb,
                               ushort_t* __restrict__ w_dtb) {
  int i = blockIdx.x * 256 + threadIdx.x;
  const int N0 = 2 * DI * DM / 4;        // w_in units
  const int N1 = N0 + DM * DI / 4;       // + w_out
  const int N2 = N1 + 128 * DI / 4;      // + w_x padded
  const int N3 = N2 + DI * DR / 4;       // + w_dt
  if (i < N0) {
    cvt4(w_in, w_inb, i);
  } else if (i < N1) {
    cvt4(w_out, w_outb, i - N0);
  } else if (i < N2) {
    int j = i - N1;
    int e0 = j << 2;
    int row = e0 >> 11;           // / DI
    int col = e0 & (DI - 1);
    ushort4 o = {0, 0, 0, 0};
    if (row < XDN) {
      float4 v = *(const float4*)(w_x + (size_t)row * DI + col);
      o.x = f2bf(v.x); o.y = f2bf(v.y); o.z = f2bf(v.z); o.w = f2bf(v.w);
    }
    ((ushort4*)w_xb)[j] = o;
  } else if (i < N3) {
    cvt4(w_dt, w_dtb, i - N2);
  }
}

// ---------------- LayerNorm: one block per row, emits bf16 ----------------
__global__ void ln_kernel(const float* __restrict__ x,
                          const float* __restrict__ gamma,
                          const float* __restrict__ beta,
                          ushort_t* __restrict__ xnb) {
  int row = blockIdx.x;
  int t = threadIdx.x;
  const float4* xr = (const float4*)(x + (size_t)row * DM);
  float4 v = xr[t];
  float s = v.x + v.y + v.z + v.w;
  float s2 = v.x * v.x + v.y * v.y + v.z * v.z + v.w * v.w;
#pragma unroll
  for (int off = 32; off > 0; off >>= 1) {
    s += __shfl_down(s, off);
    s2 += __shfl_down(s2, off);
  }
  __shared__ float ls[4], ls2[4];
  if ((t & 63) == 0) { ls[t >> 6] = s; ls2[t >> 6] = s2; }
  __syncthreads();
  float tot = ls[0] + ls[1] + ls[2] + ls[3];
  float tot2 = ls2[0] + ls2[1] + ls2[2] + ls2[3];
  float mu = tot * (1.0f / DM);
  float var = tot2 * (1.0f / DM) - mu * mu;
  float r = rsqrtf(var + 1e-5f);
  float4 g = ((const float4*)gamma)[t];
  float4 b = ((const float4*)beta)[t];
  ushort4 o;
  o.x = f2bf((v.x - mu) * r * g.x + b.x);
  o.y = f2bf((v.y - mu) * r * g.y + b.y);
  o.z = f2bf((v.z - mu) * r * g.z + b.z);
  o.w = f2bf((v.w - mu) * r * g.w + b.w);
  ((ushort4*)(xnb + (size_t)row * DM))[t] = o;
}

// ---------------- bf16 MFMA GEMM: C[M,N] = A[M,K] * B[N,K]^T ----------------
// EPI 2: fp32 store + extra[row*lde+col] (residual)
// EPI 4: bf16 store, plain
// EPI 5: bf16 store, softplus(v + extra[col])
template <int EPI>
__global__ __launch_bounds__(256) void mgemm(
    const ushort_t* __restrict__ A, int lda,
    const ushort_t* __restrict__ B, int ldb,
    void* __restrict__ Cp, int ldc, int K,
    const float* __restrict__ extra, int lde) {
  __shared__ ushort_t As[128 * 32];
  __shared__ ushort_t Bs[128 * 32];
  const int tid = threadIdx.x;
  const int lane = tid & 63;
  const int wave = tid >> 6;
  const int m0 = blockIdx.y * 128;
  const int n0 = blockIdx.x * 128;
  const int wr = (wave >> 1) * 64;
  const int wc = (wave & 1) * 64;
  const int kq = lane >> 4;
  const int rr = lane & 15;
  f32x4 acc[4][4];
#pragma unroll
  for (int i = 0; i < 4; ++i)
#pragma unroll
    for (int j = 0; j < 4; ++j) acc[i][j] = (f32x4){0.f, 0.f, 0.f, 0.f};

  const int u0 = tid, u1 = tid + 256;
  const int rA0 = u0 >> 2, cA0 = (u0 & 3) << 3;
  const int rA1 = u1 >> 2, cA1 = (u1 & 3) << 3;

  for (int k0 = 0; k0 < K; k0 += 32) {
    __syncthreads();
    __builtin_amdgcn_global_load_lds(
        (GU32*)(A + (size_t)(m0 + rA0) * lda + k0 + cA0),
        (LU32*)(As + u0 * 8), 16, 0, 0);
    __builtin_amdgcn_global_load_lds(
        (GU32*)(A + (size_t)(m0 + rA1) * lda + k0 + cA1),
        (LU32*)(As + u1 * 8), 16, 0, 0);
    __builtin_amdgcn_global_load_lds(
        (GU32*)(B + (size_t)(n0 + rA0) * ldb + k0 + cA0),
        (LU32*)(Bs + u0 * 8), 16, 0, 0);
    __builtin_amdgcn_global_load_lds(
        (GU32*)(B + (size_t)(n0 + rA1) * ldb + k0 + cA1),
        (LU32*)(Bs + u1 * 8), 16, 0, 0);
    __syncthreads();
    bf16x8 a[4], b[4];
#pragma unroll
    for (int i = 0; i < 4; ++i)
      a[i] = *(const bf16x8*)(As + (wr + i * 16 + rr) * 32 + kq * 8);
#pragma unroll
    for (int j = 0; j < 4; ++j)
      b[j] = *(const bf16x8*)(Bs + (wc + j * 16 + rr) * 32 + kq * 8);
#pragma unroll
    for (int i = 0; i < 4; ++i)
#pragma unroll
      for (int j = 0; j < 4; ++j)
        acc[i][j] = __builtin_amdgcn_mfma_f32_16x16x32_bf16(a[i], b[j], acc[i][j], 0, 0, 0);
  }
  // C/D layout: col=lane&15, row=(lane>>4)*4+reg  [m89/m91 verified]
#pragma unroll
  for (int i = 0; i < 4; ++i) {
#pragma unroll
    for (int j = 0; j < 4; ++j) {
#pragma unroll
      for (int r = 0; r < 4; ++r) {
        int row = m0 + wr + i * 16 + kq * 4 + r;
        int col = n0 + wc + j * 16 + rr;
        float v = acc[i][j][r];
        if (EPI == 2) {
          v += extra[(size_t)row * lde + col];
          ((float*)Cp)[(size_t)row * ldc + col] = v;
        } else if (EPI == 4) {
          ((ushort_t*)Cp)[(size_t)row * ldc + col] = f2bf(v);
        } else if (EPI == 5) {
          v += extra[col];
          v = (v > 20.f) ? v : __logf(1.f + __expf(v));
          ((ushort_t*)Cp)[(size_t)row * ldc + col] = f2bf(v);
        } else {
          ((float*)Cp)[(size_t)row * ldc + col] = v;
        }
      }
    }
  }
}

// ---------------- split-K MFMA GEMM for x_proj (N=128 padded, K sliced) --------
// writes fp32 partials part[s][2048][128]
__global__ __launch_bounds__(256) void mgemm_sk(
    const ushort_t* __restrict__ A, int lda,
    const ushort_t* __restrict__ B, int ldb,
    float* __restrict__ part) {
  __shared__ ushort_t As[128 * 32];
  __shared__ ushort_t Bs[128 * 32];
  const int tid = threadIdx.x;
  const int lane = tid & 63;
  const int wave = tid >> 6;
  const int m0 = blockIdx.y * 128;
  const int s = blockIdx.z;
  const int kbase = s * KSL;
  const int wr = (wave >> 1) * 64;
  const int wc = (wave & 1) * 64;
  const int kq = lane >> 4;
  const int rr = lane & 15;
  f32x4 acc[4][4];
#pragma unroll
  for (int i = 0; i < 4; ++i)
#pragma unroll
    for (int j = 0; j < 4; ++j) acc[i][j] = (f32x4){0.f, 0.f, 0.f, 0.f};

  const int u0 = tid, u1 = tid + 256;
  const int rA0 = u0 >> 2, cA0 = (u0 & 3) << 3;
  const int rA1 = u1 >> 2, cA1 = (u1 & 3) << 3;

  for (int k0 = 0; k0 < KSL; k0 += 32) {
    __syncthreads();
    __builtin_amdgcn_global_load_lds(
        (GU32*)(A + (size_t)(m0 + rA0) * lda + kbase + k0 + cA0),
        (LU32*)(As + u0 * 8), 16, 0, 0);
    __builtin_amdgcn_global_load_lds(
        (GU32*)(A + (size_t)(m0 + rA1) * lda + kbase + k0 + cA1),
        (LU32*)(As + u1 * 8), 16, 0, 0);
    __builtin_amdgcn_global_load_lds(
        (GU32*)(B + (size_t)rA0 * ldb + kbase + k0 + cA0),
        (LU32*)(Bs + u0 * 8), 16, 0, 0);
    __builtin_amdgcn_global_load_lds(
        (GU32*)(B + (size_t)rA1 * ldb + kbase + k0 + cA1),
        (LU32*)(Bs + u1 * 8), 16, 0, 0);
    __syncthreads();
    bf16x8 a[4], b[4];
#pragma unroll
    for (int i = 0; i < 4; ++i)
      a[i] = *(const bf16x8*)(As + (wr + i * 16 + rr) * 32 + kq * 8);
#pragma unroll
    for (int j = 0; j < 4; ++j)
      b[j] = *(const bf16x8*)(Bs + (wc + j * 16 + rr) * 32 + kq * 8);
#pragma unroll
    for (int i = 0; i < 4; ++i)
#pragma unroll
      for (int j = 0; j < 4; ++j)
        acc[i][j] = __builtin_amdgcn_mfma_f32_16x16x32_bf16(a[i], b[j], acc[i][j], 0, 0, 0);
  }
#pragma unroll
  for (int i = 0; i < 4; ++i)
#pragma unroll
    for (int j = 0; j < 4; ++j)
#pragma unroll
      for (int r = 0; r < 4; ++r) {
        int row = m0 + wr + i * 16 + kq * 4 + r;
        int col = wc + j * 16 + rr;
        part[((size_t)s * L_SEQ + row) * 128 + col] = acc[i][j][r];
      }
}

// reduce partials -> xdbl fp32 [2048][96] and dtb bf16 [2048][64]
__global__ void reduce_xdbl_kernel(const float* __restrict__ part,
                                   float* __restrict__ xdbl,
                                   ushort_t* __restrict__ dtb) {
  int i = blockIdx.x * 256 + threadIdx.x;  // 2048*128
  int col = i & 127;
  int row = i >> 7;
  float s = 0.f;
#pragma unroll
  for (int k = 0; k < KSLICES; ++k) s += part[(size_t)k * (L_SEQ * 128) + i];
  if (col < DR) dtb[(size_t)row * DR + col] = f2bf(s);
  if (col < XDN) xdbl[(size_t)row * XDN + col] = s;
}

// ---------------- causal depthwise conv (width 4) + bias + SiLU (bf16 in/out) ----
__global__ void conv_silu_kernel(const ushort_t* __restrict__ xzb,
                                 const float* __restrict__ conv_w,
                                 const float* __restrict__ conv_b,
                                 ushort_t* __restrict__ xconvb) {
  int i = blockIdx.x * blockDim.x + threadIdx.x;  // L_SEQ * DI/4 units
  int d0 = (i & (DI / 4 - 1)) << 2;
  int t = i >> 9;  // / (DI/4)
  float4 bia = *(const float4*)(conv_b + d0);
  float acc[4] = {bia.x, bia.y, bia.z, bia.w};
  float w[4][4];
#pragma unroll
  for (int c = 0; c < 4; ++c) {
    float4 wv = *(const float4*)(conv_w + (size_t)(d0 + c) * 4);
    w[c][0] = wv.x; w[c][1] = wv.y; w[c][2] = wv.z; w[c][3] = wv.w;
  }
#pragma unroll
  for (int j = 0; j < 4; ++j) {
    int tt = t - 3 + j;
    if (tt >= 0) {
      ushort4 xv = *(const ushort4*)(xzb + (size_t)tt * (2 * DI) + d0);
      acc[0] += bf2f(xv.x) * w[0][j];
      acc[1] += bf2f(xv.y) * w[1][j];
      acc[2] += bf2f(xv.z) * w[2][j];
      acc[3] += bf2f(xv.w) * w[3][j];
    }
  }
  ushort4 o;
  o.x = f2bf(acc[0] / (1.f + __expf(-acc[0])));
  o.y = f2bf(acc[1] / (1.f + __expf(-acc[1])));
  o.z = f2bf(acc[2] / (1.f + __expf(-acc[2])));
  o.w = f2bf(acc[3] / (1.f + __expf(-acc[3])));
  *(ushort4*)(xconvb + (size_t)t * DI + d0) = o;
}

// ---------------- chunked selective scan: one thread per channel d ----------------
__global__ void scan_chunk_kernel(const ushort_t* __restrict__ deltab,
                                  const ushort_t* __restrict__ ub,
                                  const float* __restrict__ xdbl,
                                  const float* __restrict__ A_log,
                                  float* __restrict__ P,
                                  float* __restrict__ HB) {
  int d = blockIdx.x * blockDim.x + threadIdx.x;
  int c = blockIdx.y;
  int t0 = c * TCH;
  float Aval[DS];
#pragma unroll
  for (int q = 0; q < 4; ++q) {
    float4 al = *(const float4*)(A_log + (size_t)d * DS + q * 4);
    Aval[q * 4 + 0] = -__expf(al.x);
    Aval[q * 4 + 1] = -__expf(al.y);
    Aval[q * 4 + 2] = -__expf(al.z);
    Aval[q * 4 + 3] = -__expf(al.w);
  }
  float h[DS], p[DS];
#pragma unroll
  for (int n = 0; n < DS; ++n) { h[n] = 0.f; p[n] = 1.f; }
  for (int t = t0; t < t0 + TCH; ++t) {
    float dlt = bf2f(deltab[(size_t)t * DI + d]);
    float uv = bf2f(ub[(size_t)t * DI + d]);
    float du = dlt * uv;
    float Bv[DS];
#pragma unroll
    for (int q = 0; q < 4; ++q) {
      float4 b4 = *(const float4*)(xdbl + (size_t)t * XDN + DR + q * 4);
      Bv[q * 4 + 0] = b4.x; Bv[q * 4 + 1] = b4.y;
      Bv[q * 4 + 2] = b4.z; Bv[q * 4 + 3] = b4.w;
    }
#pragma unroll
    for (int n = 0; n < DS; ++n) {
      float dA = __expf(dlt * Aval[n]);
      p[n] *= dA;
      h[n] = dA * h[n] + du * Bv[n];
    }
  }
#pragma unroll
  for (int n = 0; n < DS; ++n) {
    size_t idx = ((size_t)c * DS + n) * DI + d;
    P[idx] = p[n];
    HB[idx] = h[n];
  }
}

__global__ void scan_prop_kernel(const float* __restrict__ P,
                                 const float* __restrict__ HB,
                                 float* __restrict__ HIN) {
  int dn = blockIdx.x * blockDim.x + threadIdx.x;
  float h = 0.f;
#pragma unroll 4
  for (int c = 0; c < NCHUNK; ++c) {
    size_t idx = (size_t)c * (DI * DS) + dn;
    HIN[idx] = h;
    h = P[idx] * h + HB[idx];
  }
}

__global__ void scan_final_kernel(const ushort_t* __restrict__ deltab,
                                  const ushort_t* __restrict__ ub,
                                  const float* __restrict__ xdbl,
                                  const ushort_t* __restrict__ xzb,
                                  const float* __restrict__ A_log,
                                  const float* __restrict__ Dp,
                                  const float* __restrict__ HIN,
                                  ushort_t* __restrict__ ygb) {
  int d = blockIdx.x * blockDim.x + threadIdx.x;
  int c = blockIdx.y;
  int t0 = c * TCH;
  float Aval[DS];
#pragma unroll
  for (int q = 0; q < 4; ++q) {
    float4 al = *(const float4*)(A_log + (size_t)d * DS + q * 4);
    Aval[q * 4 + 0] = -__expf(al.x);
    Aval[q * 4 + 1] = -__expf(al.y);
    Aval[q * 4 + 2] = -__expf(al.z);
    Aval[q * 4 + 3] = -__expf(al.w);
  }
  float Dval = Dp[d];
  float h[DS];
#pragma unroll
  for (int n = 0; n < DS; ++n) h[n] = HIN[((size_t)c * DS + n) * DI + d];
  for (int t = t0; t < t0 + TCH; ++t) {
    float dlt = bf2f(deltab[(size_t)t * DI + d]);
    float uv = bf2f(ub[(size_t)t * DI + d]);
    float du = dlt * uv;
    float Bv[DS], Cv[DS];
#pragma unroll
    for (int q = 0; q < 4; ++q) {
      float4 b4 = *(const float4*)(xdbl + (size_t)t * XDN + DR + q * 4);
      float4 c4 = *(const float4*)(xdbl + (size_t)t * XDN + DR + DS + q * 4);
      Bv[q * 4 + 0] = b4.x; Bv[q * 4 + 1] = b4.y;
      Bv[q * 4 + 2] = b4.z; Bv[q * 4 + 3] = b4.w;
      Cv[q * 4 + 0] = c4.x; Cv[q * 4 + 1] = c4.y;
      Cv[q * 4 + 2] = c4.z; Cv[q * 4 + 3] = c4.w;
    }
    float acc = uv * Dval;
#pragma unroll
    for (int n = 0; n < DS; ++n) {
      float dA = __expf(dlt * Aval[n]);
      h[n] = dA * h[n] + du * Bv[n];
      acc += h[n] * Cv[n];
    }
    float z = bf2f(xzb[(size_t)t * (2 * DI) + DI + d]);
    float sz = z / (1.f + __expf(-z));
    ygb[(size_t)t * DI + d] = f2bf(acc * sz);
  }
}

extern "C" void kernel_launch(void* const* d_in, const int* in_sizes, int n_in,
                              void* d_out, int out_size, void* d_ws, size_t ws_size,
                              hipStream_t stream) {
  const float* x = (const float*)d_in[0];
  const float* gamma = (const float*)d_in[1];
  const float* beta = (const float*)d_in[2];
  const float* w_in = (const float*)d_in[3];
  const float* conv_w = (const float*)d_in[4];
  const float* conv_b = (const float*)d_in[5];
  const float* w_x = (const float*)d_in[6];
  const float* w_dt = (const float*)d_in[7];
  const float* b_dt = (const float*)d_in[8];
  const float* A_log = (const float*)d_in[9];
  const float* Dp = (const float*)d_in[10];
  const float* w_out = (const float*)d_in[11];
  float* out = (float*)d_out;

  float* ws = (float*)d_ws;
  float* xdbl = ws;                                   // 2048*96
  float* P = xdbl + (size_t)L_SEQ * XDN;              // 64*16*2048
  float* HB = P + (size_t)NCHUNK * DI * DS;
  float* HIN = HB + (size_t)NCHUNK * DI * DS;
  float* part = HIN + (size_t)NCHUNK * DI * DS;       // 8*2048*128
  ushort_t* xzb = (ushort_t*)(part + (size_t)KSLICES * L_SEQ * 128);  // 2048*4096
  ushort_t* xconvb = xzb + (size_t)L_SEQ * 2 * DI;    // 2048*2048
  ushort_t* deltab = xconvb + (size_t)L_SEQ * DI;     // 2048*2048
  ushort_t* ygb = deltab + (size_t)L_SEQ * DI;        // 2048*2048
  ushort_t* xnb = ygb + (size_t)L_SEQ * DI;           // 2048*1024
  ushort_t* w_inb = xnb + (size_t)L_SEQ * DM;         // 4096*1024
  ushort_t* w_outb = w_inb + (size_t)(2 * DI) * DM;   // 1024*2048
  ushort_t* w_xb = w_outb + (size_t)DM * DI;          // 128*2048
  ushort_t* w_dtb = w_xb + (size_t)128 * DI;          // 2048*64
  ushort_t* dtb = w_dtb + (size_t)DI * DR;            // 2048*64

  // 0. all weight conversions (one launch)
  {
    int units = (2 * DI * DM + DM * DI + 128 * DI + DI * DR) / 4;
    cvt_all_kernel<<<(units + 255) / 256, 256, 0, stream>>>(
        w_in, w_out, w_x, w_dt, w_inb, w_outb, w_xb, w_dtb);
  }
  // 1. LayerNorm -> bf16
  ln_kernel<<<L_SEQ, 256, 0, stream>>>(x, gamma, beta, xnb);
  // 2. xz = xn @ w_in^T  (2048 x 4096, K=1024) -> bf16
  mgemm<4><<<dim3((2 * DI) / 128, L_SEQ / 128), 256, 0, stream>>>(
      xnb, DM, w_inb, DM, xzb, 2 * DI, DM, nullptr, 0);
  // 3. conv + silu -> xconvb (bf16)
  conv_silu_kernel<<<(L_SEQ * DI / 4) / 256, 256, 0, stream>>>(
      xzb, conv_w, conv_b, xconvb);
  // 4. x_dbl partials: split-K (2048 x 128, K sliced 8x256)
  mgemm_sk<<<dim3(1, L_SEQ / 128, KSLICES), 256, 0, stream>>>(
      xconvb, DI, w_xb, DI, part);
  reduce_xdbl_kernel<<<(L_SEQ * 128) / 256, 256, 0, stream>>>(part, xdbl, dtb);
  // 5. delta = softplus(dt @ w_dt^T + b_dt)  (2048 x 2048, K=64) -> bf16
  mgemm<5><<<dim3(DI / 128, L_SEQ / 128), 256, 0, stream>>>(
      dtb, DR, w_dtb, DR, deltab, DI, DR, b_dt, 0);
  // 6. chunked selective scan + gate -> ygb (bf16)
  scan_chunk_kernel<<<dim3(DI / 256, NCHUNK), 256, 0, stream>>>(
      deltab, xconvb, xdbl, A_log, P, HB);
  scan_prop_kernel<<<(DI * DS) / 256, 256, 0, stream>>>(P, HB, HIN);
  scan_final_kernel<<<dim3(DI / 256, NCHUNK), 256, 0, stream>>>(
      deltab, xconvb, xdbl, xzb, A_log, Dp, HIN, ygb);
  // 7. out = yg @ w_out^T + residual  (2048 x 1024, K=2048)
  mgemm<2><<<dim3(DM / 128, L_SEQ / 128), 256, 0, stream>>>(
      ygb, DI, w_outb, DI, out, DM, DI, x, DM);
}

// Round 6
// 161.309 us; speedup vs baseline: 13.2798x; 1.1179x over previous
//
#include <hip/hip_runtime.h>
#include <math.h>

#define L_SEQ 2048
#define DM 1024      // D_MODEL
#define DI 2048      // D_INNER
#define DS 16        // D_STATE
#define DR 64        // DT_RANK
#define XDN 96       // DT_RANK + 2*D_STATE
#define NCHUNK 64
#define TCH 32       // L_SEQ / NCHUNK
#define KSLICES 8
#define KSL (DI / KSLICES)   // 256

typedef __attribute__((ext_vector_type(8))) short bf16x8;
typedef __attribute__((ext_vector_type(4))) float f32x4;
typedef unsigned short ushort_t;
typedef __attribute__((address_space(1))) const unsigned int GU32;
typedef __attribute__((address_space(3))) unsigned int LU32;

__device__ inline unsigned short f2bf(float f) {
  unsigned int u = __builtin_bit_cast(unsigned int, f);
  u += 0x7fffu + ((u >> 16) & 1u);  // round-to-nearest-even
  return (unsigned short)(u >> 16);
}
__device__ inline float bf2f(unsigned short u) {
  return __builtin_bit_cast(float, (unsigned int)u << 16);
}

// ---------------- fused weight conversion (one launch) ----------------
__device__ inline void cvt4(const float* src, ushort_t* dst, int j) {
  float4 v = ((const float4*)src)[j];
  ushort4 o;
  o.x = f2bf(v.x); o.y = f2bf(v.y); o.z = f2bf(v.z); o.w = f2bf(v.w);
  ((ushort4*)dst)[j] = o;
}

__global__ void cvt_all_kernel(const float* __restrict__ w_in,
                               const float* __restrict__ w_out,
                               const float* __restrict__ w_x,
                               const float* __restrict__ w_dt,
                               ushort_t* __restrict__ w_inb,
                               ushort_t* __restrict__ w_outb,
                               ushort_t* __restrict__ w_xb,
                               ushort_t* __restrict__ w_dtb) {
  int i = blockIdx.x * 256 + threadIdx.x;
  const int N0 = 2 * DI * DM / 4;        // w_in units
  const int N1 = N0 + DM * DI / 4;       // + w_out
  const int N2 = N1 + 128 * DI / 4;      // + w_x padded
  const int N3 = N2 + DI * DR / 4;       // + w_dt
  if (i < N0) {
    cvt4(w_in, w_inb, i);
  } else if (i < N1) {
    cvt4(w_out, w_outb, i - N0);
  } else if (i < N2) {
    int j = i - N1;
    int e0 = j << 2;
    int row = e0 >> 11;           // / DI
    int col = e0 & (DI - 1);
    ushort4 o = {0, 0, 0, 0};
    if (row < XDN) {
      float4 v = *(const float4*)(w_x + (size_t)row * DI + col);
      o.x = f2bf(v.x); o.y = f2bf(v.y); o.z = f2bf(v.z); o.w = f2bf(v.w);
    }
    ((ushort4*)w_xb)[j] = o;
  } else if (i < N3) {
    cvt4(w_dt, w_dtb, i - N2);
  }
}

// ---------------- LayerNorm: one block per row, emits bf16 ----------------
__global__ void ln_kernel(const float* __restrict__ x,
                          const float* __restrict__ gamma,
                          const float* __restrict__ beta,
                          ushort_t* __restrict__ xnb) {
  int row = blockIdx.x;
  int t = threadIdx.x;
  const float4* xr = (const float4*)(x + (size_t)row * DM);
  float4 v = xr[t];
  float s = v.x + v.y + v.z + v.w;
  float s2 = v.x * v.x + v.y * v.y + v.z * v.z + v.w * v.w;
#pragma unroll
  for (int off = 32; off > 0; off >>= 1) {
    s += __shfl_down(s, off);
    s2 += __shfl_down(s2, off);
  }
  __shared__ float ls[4], ls2[4];
  if ((t & 63) == 0) { ls[t >> 6] = s; ls2[t >> 6] = s2; }
  __syncthreads();
  float tot = ls[0] + ls[1] + ls[2] + ls[3];
  float tot2 = ls2[0] + ls2[1] + ls2[2] + ls2[3];
  float mu = tot * (1.0f / DM);
  float var = tot2 * (1.0f / DM) - mu * mu;
  float r = rsqrtf(var + 1e-5f);
  float4 g = ((const float4*)gamma)[t];
  float4 b = ((const float4*)beta)[t];
  ushort4 o;
  o.x = f2bf((v.x - mu) * r * g.x + b.x);
  o.y = f2bf((v.y - mu) * r * g.y + b.y);
  o.z = f2bf((v.z - mu) * r * g.z + b.z);
  o.w = f2bf((v.w - mu) * r * g.w + b.w);
  ((ushort4*)(xnb + (size_t)row * DM))[t] = o;
}

// ---------------- bf16 MFMA GEMM: C[M,N] = A[M,K] * B[N,K]^T ----------------
// 128x128 tile, BK=64, 4 waves, global_load_lds 16B, XOR-swizzled LDS
// (linear dest + inverse-swizzled source + swizzled read; rule #21).
// split-K via blockIdx.z: kbase = z*ksl, EPI6 writes fp32 partial slice z.
// EPI 4: bf16 store, plain
// EPI 5: bf16 store, softplus(v + extra[col])
// EPI 6: fp32 partial store at part[z][row][ldc]
template <int EPI>
__global__ __launch_bounds__(256) void mgemm(
    const ushort_t* __restrict__ A, int lda,
    const ushort_t* __restrict__ B, int ldb,
    void* __restrict__ Cp, int ldc, int ksl,
    const float* __restrict__ extra) {
  __shared__ ushort_t As[128 * 64];
  __shared__ ushort_t Bs[128 * 64];
  const int tid = threadIdx.x;
  const int lane = tid & 63;
  const int wave = tid >> 6;
  const int m0 = blockIdx.y * 128;
  const int n0 = blockIdx.x * 128;
  const int kbase = blockIdx.z * ksl;
  const int wr = (wave >> 1) * 64;
  const int wc = (wave & 1) * 64;
  const int kq = lane >> 4;
  const int rr = lane & 15;
  f32x4 acc[4][4];
#pragma unroll
  for (int i = 0; i < 4; ++i)
#pragma unroll
    for (int j = 0; j < 4; ++j) acc[i][j] = (f32x4){0.f, 0.f, 0.f, 0.f};

  // staging: 1024 units of 16B per tile; unit u: row = u>>3, phys slot = u&7.
  // source slot = phys ^ (row&7)  (same involution applied on read)
  int ur[4], uc[4];
#pragma unroll
  for (int q = 0; q < 4; ++q) {
    int u = tid + 256 * q;
    ur[q] = u >> 3;
    uc[q] = (((u & 7) ^ (ur[q] & 7)) << 3);  // source col in elems
  }

  for (int k0 = kbase; k0 < kbase + ksl; k0 += 64) {
    __syncthreads();
#pragma unroll
    for (int q = 0; q < 4; ++q)
      __builtin_amdgcn_global_load_lds(
          (GU32*)(A + (size_t)(m0 + ur[q]) * lda + k0 + uc[q]),
          (LU32*)(As + (tid + 256 * q) * 8), 16, 0, 0);
#pragma unroll
    for (int q = 0; q < 4; ++q)
      __builtin_amdgcn_global_load_lds(
          (GU32*)(B + (size_t)(n0 + ur[q]) * ldb + k0 + uc[q]),
          (LU32*)(Bs + (tid + 256 * q) * 8), 16, 0, 0);
    __syncthreads();
#pragma unroll
    for (int kk = 0; kk < 2; ++kk) {
      const int sw = ((rr & 7) << 4);
      bf16x8 a[4], b[4];
#pragma unroll
      for (int i = 0; i < 4; ++i) {
        int row = wr + i * 16 + rr;
        int off = ((kk * 64 + kq * 16) ^ sw);
        a[i] = *(const bf16x8*)((const char*)As + row * 128 + off);
      }
#pragma unroll
      for (int j = 0; j < 4; ++j) {
        int row = wc + j * 16 + rr;
        int off = ((kk * 64 + kq * 16) ^ sw);
        b[j] = *(const bf16x8*)((const char*)Bs + row * 128 + off);
      }
#pragma unroll
      for (int i = 0; i < 4; ++i)
#pragma unroll
        for (int j = 0; j < 4; ++j)
          acc[i][j] = __builtin_amdgcn_mfma_f32_16x16x32_bf16(a[i], b[j], acc[i][j], 0, 0, 0);
    }
  }
  // C/D layout: col=lane&15, row=(lane>>4)*4+reg  [m89/m91 verified]
#pragma unroll
  for (int i = 0; i < 4; ++i) {
#pragma unroll
    for (int j = 0; j < 4; ++j) {
#pragma unroll
      for (int r = 0; r < 4; ++r) {
        int row = m0 + wr + i * 16 + kq * 4 + r;
        int col = n0 + wc + j * 16 + rr;
        float v = acc[i][j][r];
        if (EPI == 4) {
          ((ushort_t*)Cp)[(size_t)row * ldc + col] = f2bf(v);
        } else if (EPI == 5) {
          v += extra[col];
          v = (v > 20.f) ? v : __logf(1.f + __expf(v));
          ((ushort_t*)Cp)[(size_t)row * ldc + col] = f2bf(v);
        } else if (EPI == 6) {
          ((float*)Cp)[((size_t)blockIdx.z * L_SEQ + row) * ldc + col] = v;
        }
      }
    }
  }
}

// reduce x_proj partials -> xdbl fp32 [2048][96] and dtb bf16 [2048][64]
__global__ void reduce_xdbl_kernel(const float* __restrict__ part,
                                   float* __restrict__ xdbl,
                                   ushort_t* __restrict__ dtb) {
  int i = blockIdx.x * 256 + threadIdx.x;  // 2048*128
  int col = i & 127;
  int row = i >> 7;
  float s = 0.f;
#pragma unroll
  for (int k = 0; k < KSLICES; ++k) s += part[(size_t)k * (L_SEQ * 128) + i];
  if (col < DR) dtb[(size_t)row * DR + col] = f2bf(s);
  if (col < XDN) xdbl[(size_t)row * XDN + col] = s;
}

// reduce out_proj partials (2 slices) + residual -> out fp32
__global__ void reduce_out_kernel(const float* __restrict__ part,
                                  const float* __restrict__ x,
                                  float* __restrict__ out) {
  int i = blockIdx.x * 256 + threadIdx.x;  // over 2048*1024/4
  float4 p0 = ((const float4*)part)[i];
  float4 p1 = ((const float4*)(part + (size_t)L_SEQ * DM))[i];
  float4 xr = ((const float4*)x)[i];
  float4 o;
  o.x = p0.x + p1.x + xr.x;
  o.y = p0.y + p1.y + xr.y;
  o.z = p0.z + p1.z + xr.z;
  o.w = p0.w + p1.w + xr.w;
  ((float4*)out)[i] = o;
}

// ---------------- causal depthwise conv (width 4) + bias + SiLU (bf16 in/out) ----
__global__ void conv_silu_kernel(const ushort_t* __restrict__ xzb,
                                 const float* __restrict__ conv_w,
                                 const float* __restrict__ conv_b,
                                 ushort_t* __restrict__ xconvb) {
  int i = blockIdx.x * blockDim.x + threadIdx.x;  // L_SEQ * DI/4 units
  int d0 = (i & (DI / 4 - 1)) << 2;
  int t = i >> 9;  // / (DI/4)
  float4 bia = *(const float4*)(conv_b + d0);
  float acc[4] = {bia.x, bia.y, bia.z, bia.w};
  float w[4][4];
#pragma unroll
  for (int c = 0; c < 4; ++c) {
    float4 wv = *(const float4*)(conv_w + (size_t)(d0 + c) * 4);
    w[c][0] = wv.x; w[c][1] = wv.y; w[c][2] = wv.z; w[c][3] = wv.w;
  }
#pragma unroll
  for (int j = 0; j < 4; ++j) {
    int tt = t - 3 + j;
    if (tt >= 0) {
      ushort4 xv = *(const ushort4*)(xzb + (size_t)tt * (2 * DI) + d0);
      acc[0] += bf2f(xv.x) * w[0][j];
      acc[1] += bf2f(xv.y) * w[1][j];
      acc[2] += bf2f(xv.z) * w[2][j];
      acc[3] += bf2f(xv.w) * w[3][j];
    }
  }
  ushort4 o;
  o.x = f2bf(acc[0] / (1.f + __expf(-acc[0])));
  o.y = f2bf(acc[1] / (1.f + __expf(-acc[1])));
  o.z = f2bf(acc[2] / (1.f + __expf(-acc[2])));
  o.w = f2bf(acc[3] / (1.f + __expf(-acc[3])));
  *(ushort4*)(xconvb + (size_t)t * DI + d0) = o;
}

// ---------------- chunked selective scan: one thread per channel d ----------------
__global__ void scan_chunk_kernel(const ushort_t* __restrict__ deltab,
                                  const ushort_t* __restrict__ ub,
                                  const float* __restrict__ xdbl,
                                  const float* __restrict__ A_log,
                                  float* __restrict__ P,
                                  float* __restrict__ HB) {
  int d = blockIdx.x * blockDim.x + threadIdx.x;
  int c = blockIdx.y;
  int t0 = c * TCH;
  float Aval[DS];
#pragma unroll
  for (int q = 0; q < 4; ++q) {
    float4 al = *(const float4*)(A_log + (size_t)d * DS + q * 4);
    Aval[q * 4 + 0] = -__expf(al.x);
    Aval[q * 4 + 1] = -__expf(al.y);
    Aval[q * 4 + 2] = -__expf(al.z);
    Aval[q * 4 + 3] = -__expf(al.w);
  }
  float h[DS], p[DS];
#pragma unroll
  for (int n = 0; n < DS; ++n) { h[n] = 0.f; p[n] = 1.f; }
  for (int t = t0; t < t0 + TCH; ++t) {
    float dlt = bf2f(deltab[(size_t)t * DI + d]);
    float uv = bf2f(ub[(size_t)t * DI + d]);
    float du = dlt * uv;
    float Bv[DS];
#pragma unroll
    for (int q = 0; q < 4; ++q) {
      float4 b4 = *(const float4*)(xdbl + (size_t)t * XDN + DR + q * 4);
      Bv[q * 4 + 0] = b4.x; Bv[q * 4 + 1] = b4.y;
      Bv[q * 4 + 2] = b4.z; Bv[q * 4 + 3] = b4.w;
    }
#pragma unroll
    for (int n = 0; n < DS; ++n) {
      float dA = __expf(dlt * Aval[n]);
      p[n] *= dA;
      h[n] = dA * h[n] + du * Bv[n];
    }
  }
#pragma unroll
  for (int n = 0; n < DS; ++n) {
    size_t idx = ((size_t)c * DS + n) * DI + d;
    P[idx] = p[n];
    HB[idx] = h[n];
  }
}

__global__ void scan_prop_kernel(const float* __restrict__ P,
                                 const float* __restrict__ HB,
                                 float* __restrict__ HIN) {
  int dn = blockIdx.x * blockDim.x + threadIdx.x;
  float h = 0.f;
#pragma unroll 4
  for (int c = 0; c < NCHUNK; ++c) {
    size_t idx = (size_t)c * (DI * DS) + dn;
    HIN[idx] = h;
    h = P[idx] * h + HB[idx];
  }
}

__global__ void scan_final_kernel(const ushort_t* __restrict__ deltab,
                                  const ushort_t* __restrict__ ub,
                                  const float* __restrict__ xdbl,
                                  const ushort_t* __restrict__ xzb,
                                  const float* __restrict__ A_log,
                                  const float* __restrict__ Dp,
                                  const float* __restrict__ HIN,
                                  ushort_t* __restrict__ ygb) {
  int d = blockIdx.x * blockDim.x + threadIdx.x;
  int c = blockIdx.y;
  int t0 = c * TCH;
  float Aval[DS];
#pragma unroll
  for (int q = 0; q < 4; ++q) {
    float4 al = *(const float4*)(A_log + (size_t)d * DS + q * 4);
    Aval[q * 4 + 0] = -__expf(al.x);
    Aval[q * 4 + 1] = -__expf(al.y);
    Aval[q * 4 + 2] = -__expf(al.z);
    Aval[q * 4 + 3] = -__expf(al.w);
  }
  float Dval = Dp[d];
  float h[DS];
#pragma unroll
  for (int n = 0; n < DS; ++n) h[n] = HIN[((size_t)c * DS + n) * DI + d];
  for (int t = t0; t < t0 + TCH; ++t) {
    float dlt = bf2f(deltab[(size_t)t * DI + d]);
    float uv = bf2f(ub[(size_t)t * DI + d]);
    float du = dlt * uv;
    float Bv[DS], Cv[DS];
#pragma unroll
    for (int q = 0; q < 4; ++q) {
      float4 b4 = *(const float4*)(xdbl + (size_t)t * XDN + DR + q * 4);
      float4 c4 = *(const float4*)(xdbl + (size_t)t * XDN + DR + DS + q * 4);
      Bv[q * 4 + 0] = b4.x; Bv[q * 4 + 1] = b4.y;
      Bv[q * 4 + 2] = b4.z; Bv[q * 4 + 3] = b4.w;
      Cv[q * 4 + 0] = c4.x; Cv[q * 4 + 1] = c4.y;
      Cv[q * 4 + 2] = c4.z; Cv[q * 4 + 3] = c4.w;
    }
    float acc = uv * Dval;
#pragma unroll
    for (int n = 0; n < DS; ++n) {
      float dA = __expf(dlt * Aval[n]);
      h[n] = dA * h[n] + du * Bv[n];
      acc += h[n] * Cv[n];
    }
    float z = bf2f(xzb[(size_t)t * (2 * DI) + DI + d]);
    float sz = z / (1.f + __expf(-z));
    ygb[(size_t)t * DI + d] = f2bf(acc * sz);
  }
}

extern "C" void kernel_launch(void* const* d_in, const int* in_sizes, int n_in,
                              void* d_out, int out_size, void* d_ws, size_t ws_size,
                              hipStream_t stream) {
  const float* x = (const float*)d_in[0];
  const float* gamma = (const float*)d_in[1];
  const float* beta = (const float*)d_in[2];
  const float* w_in = (const float*)d_in[3];
  const float* conv_w = (const float*)d_in[4];
  const float* conv_b = (const float*)d_in[5];
  const float* w_x = (const float*)d_in[6];
  const float* w_dt = (const float*)d_in[7];
  const float* b_dt = (const float*)d_in[8];
  const float* A_log = (const float*)d_in[9];
  const float* Dp = (const float*)d_in[10];
  const float* w_out = (const float*)d_in[11];
  float* out = (float*)d_out;

  float* ws = (float*)d_ws;
  float* xdbl = ws;                                   // 2048*96
  float* P = xdbl + (size_t)L_SEQ * XDN;              // 64*16*2048
  float* HB = P + (size_t)NCHUNK * DI * DS;
  float* HIN = HB + (size_t)NCHUNK * DI * DS;
  float* part = HIN + (size_t)NCHUNK * DI * DS;       // 8*2048*128
  ushort_t* xzb = (ushort_t*)(part + (size_t)KSLICES * L_SEQ * 128);  // 2048*4096
  ushort_t* xconvb = xzb + (size_t)L_SEQ * 2 * DI;    // 2048*2048
  ushort_t* deltab = xconvb + (size_t)L_SEQ * DI;     // 2048*2048
  ushort_t* ygb = deltab + (size_t)L_SEQ * DI;        // 2048*2048
  ushort_t* xnb = ygb + (size_t)L_SEQ * DI;           // 2048*1024
  ushort_t* w_inb = xnb + (size_t)L_SEQ * DM;         // 4096*1024
  ushort_t* w_outb = w_inb + (size_t)(2 * DI) * DM;   // 1024*2048
  ushort_t* w_xb = w_outb + (size_t)DM * DI;          // 128*2048
  ushort_t* w_dtb = w_xb + (size_t)128 * DI;          // 2048*64
  ushort_t* dtb = w_dtb + (size_t)DI * DR;            // 2048*64
  // out_proj partials (2 x 2048 x 1024 fp32) alias xzb: xzb is dead after
  // scan_final, and 2*2048*1024*4B == 2048*4096*2B exactly.
  float* part_out = (float*)xzb;

  // 0. all weight conversions (one launch)
  {
    int units = (2 * DI * DM + DM * DI + 128 * DI + DI * DR) / 4;
    cvt_all_kernel<<<(units + 255) / 256, 256, 0, stream>>>(
        w_in, w_out, w_x, w_dt, w_inb, w_outb, w_xb, w_dtb);
  }
  // 1. LayerNorm -> bf16
  ln_kernel<<<L_SEQ, 256, 0, stream>>>(x, gamma, beta, xnb);
  // 2. xz = xn @ w_in^T  (2048 x 4096, K=1024) -> bf16
  mgemm<4><<<dim3((2 * DI) / 128, L_SEQ / 128, 1), 256, 0, stream>>>(
      xnb, DM, w_inb, DM, xzb, 2 * DI, DM, nullptr);
  // 3. conv + silu -> xconvb (bf16)
  conv_silu_kernel<<<(L_SEQ * DI / 4) / 256, 256, 0, stream>>>(
      xzb, conv_w, conv_b, xconvb);
  // 4. x_dbl partials: split-K (2048 x 128, K sliced 8x256) -> reduce
  mgemm<6><<<dim3(1, L_SEQ / 128, KSLICES), 256, 0, stream>>>(
      xconvb, DI, w_xb, DI, part, 128, KSL, nullptr);
  reduce_xdbl_kernel<<<(L_SEQ * 128) / 256, 256, 0, stream>>>(part, xdbl, dtb);
  // 5. delta = softplus(dt @ w_dt^T + b_dt)  (2048 x 2048, K=64) -> bf16
  mgemm<5><<<dim3(DI / 128, L_SEQ / 128, 1), 256, 0, stream>>>(
      dtb, DR, w_dtb, DR, deltab, DI, DR, b_dt);
  // 6. chunked selective scan + gate -> ygb (bf16)
  scan_chunk_kernel<<<dim3(DI / 256, NCHUNK), 256, 0, stream>>>(
      deltab, xconvb, xdbl, A_log, P, HB);
  scan_prop_kernel<<<(DI * DS) / 256, 256, 0, stream>>>(P, HB, HIN);
  scan_final_kernel<<<dim3(DI / 256, NCHUNK), 256, 0, stream>>>(
      deltab, xconvb, xdbl, xzb, A_log, Dp, HIN, ygb);
  // 7. out_proj split-K x2 (2048 x 1024, K=2048) -> partials, then +residual
  mgemm<6><<<dim3(DM / 128, L_SEQ / 128, 2), 256, 0, stream>>>(
      ygb, DI, w_outb, DI, part_out, DM, DI / 2, nullptr);
  reduce_out_kernel<<<(L_SEQ * DM / 4) / 256, 256, 0, stream>>>(part_out, x, out);
}